// Round 6
// baseline (1233.146 us; speedup 1.0000x reference)
//
#include <hip/hip_runtime.h>
#include <hip/hip_bf16.h>
#include <math.h>

#define S_LEN 2048
#define BATCH 2
#define HDIM 1024
#define FDIM 3072
#define MAXK 819
#define MAXSPAN 30
#define NEGV -10000.0f

typedef __attribute__((ext_vector_type(8))) short short8;
typedef __attribute__((ext_vector_type(4))) float f32x4;
typedef __hip_bfloat16 hb;

__device__ __forceinline__ float gelu_f(float x) {
  return 0.5f * x * (1.0f + erff(x * 0.70710678118654752440f));
}

__device__ __forceinline__ unsigned short bf_bits(float x) {
  hb b = __float2bfloat16(x);
  return *reinterpret_cast<unsigned short*>(&b);
}
__device__ __forceinline__ float bf_back(unsigned short u) {
  hb b = *reinterpret_cast<hb*>(&u);
  return __bfloat162float(b);
}

__device__ __forceinline__ void gload16(const void* g, void* l) {
  __builtin_amdgcn_global_load_lds(
      (const __attribute__((address_space(1))) void*)g,
      (__attribute__((address_space(3))) void*)l, 16, 0, 0);
}

// ---------------------------------------------------------------------------
// bf16 MFMA GEMM, single-term, BK=128 (128 MFMA per barrier-pair).
// C[M,N] = act(A[M,K] @ B[N,K]^T + bias).  K multiple of 128.
// z-batching: blockIdx.z = zb*kspl + zk; operands at zb*sA/sB, k-slice zk,
// C slice at blockIdx.z * sC.  bias2 (if non-null) replaces bias for zb>=1.
// NOTE: XCD-chunked blockIdx remap was tried (r1/r2) and REGRESSED here:
// inputs are L3-resident and kernel is not HBM-bound; chunking de-correlates
// the XCDs' B-panel streams (FETCH 240->326 MB). Keep default dispatch order.
// ---------------------------------------------------------------------------
__global__ __launch_bounds__(256) void gemm_fast1(
    const hb* __restrict__ A, const hb* __restrict__ B,
    const float* __restrict__ bias, const float* __restrict__ bias2,
    void* __restrict__ Cv,
    int M, int N, int K, int lda, int ldb, int ldc,
    long long sA, long long sB, long long sC,
    int act, int out_mode, int kspl)
{
  const int zb = blockIdx.z / kspl, zk = blockIdx.z - zb * kspl;
  A += (long long)zb * sA + (long long)zk * K;
  B += (long long)zb * sB + (long long)zk * K;
  const long long cbase = (long long)blockIdx.z * sC;
  const float* bp = (bias2 && zb) ? bias2 : bias;
  const int bm = blockIdx.y * 128, bn = blockIdx.x * 128;
  const int tid = threadIdx.x;
  const int lane = tid & 63;
  const int wv = tid >> 6, wr = wv >> 1, wc = wv & 1;
  const int lrow = lane & 15, lk = lane >> 4;
  __shared__ __align__(16) hb As[128 * 128];
  __shared__ __align__(16) hb Bs[128 * 128];

  const int srow = tid >> 4;          // 0..15
  const int sc8 = tid & 15;           // 16 slots of 8 bf16
  const int sslot = (sc8 - srow) & 15;  // inverse swizzle on global source

  f32x4 acc[4][4];
#pragma unroll
  for (int mi = 0; mi < 4; ++mi)
#pragma unroll
    for (int ni = 0; ni < 4; ++ni) acc[mi][ni] = (f32x4){0.f, 0.f, 0.f, 0.f};

  long long aoff[8], boff[8];
#pragma unroll
  for (int it = 0; it < 8; ++it) {
    int gm = bm + srow + it * 16; if (gm > M - 1) gm = M - 1;
    int gn = bn + srow + it * 16; if (gn > N - 1) gn = N - 1;
    aoff[it] = (long long)gm * lda + sslot * 8;
    boff[it] = (long long)gn * ldb + sslot * 8;
  }

  for (int k0 = 0; k0 < K; k0 += 128) {
#pragma unroll
    for (int it = 0; it < 8; ++it)
      gload16(A + aoff[it] + k0, &As[(tid + it * 256) * 8]);
#pragma unroll
    for (int it = 0; it < 8; ++it)
      gload16(B + boff[it] + k0, &Bs[(tid + it * 256) * 8]);
    __syncthreads();
#pragma unroll
    for (int ks = 0; ks < 4; ++ks) {
      const int sa = ((ks * 4 + lk + lrow) & 15) * 8;   // swizzled read slot
      short8 a[4], b[4];
#pragma unroll
      for (int mi = 0; mi < 4; ++mi)
        a[mi] = *(const short8*)&As[(wr * 64 + mi * 16 + lrow) * 128 + sa];
#pragma unroll
      for (int ni = 0; ni < 4; ++ni)
        b[ni] = *(const short8*)&Bs[(wc * 64 + ni * 16 + lrow) * 128 + sa];
#pragma unroll
      for (int mi = 0; mi < 4; ++mi)
#pragma unroll
        for (int ni = 0; ni < 4; ++ni)
          acc[mi][ni] = __builtin_amdgcn_mfma_f32_16x16x32_bf16(
              a[mi], b[ni], acc[mi][ni], 0, 0, 0);
    }
    __syncthreads();
  }

  float* Cf = (float*)Cv;
  hb* Cb = (hb*)Cv;
#pragma unroll
  for (int mi = 0; mi < 4; ++mi) {
#pragma unroll
    for (int ni = 0; ni < 4; ++ni) {
#pragma unroll
      for (int q = 0; q < 4; ++q) {
        int gm = bm + wr * 64 + mi * 16 + lk * 4 + q;
        int gn = bn + wc * 64 + ni * 16 + lrow;
        if (gm < M && gn < N) {
          float v = acc[mi][ni][q];
          if (bp)   v += bp[gn];
          if (act)  v = gelu_f(v);
          long long off = cbase + (long long)gm * ldc + gn;
          if (out_mode == 1) Cb[off] = __float2bfloat16(v);
          else               Cf[off] = v;
        }
      }
    }
  }
}

// ---------------------------------------------------------------------------
// Fused split-bf16 3-term GEMM (fp32-equivalent): stages A_hi,A_lo,B_hi,B_lo
// once per K-tile (64KB LDS), 96 MFMAs per K-tile (hh + lh + hl). BK=64.
// out_mode: 0 = f32, 2 = split hi/lo bf16.
// ---------------------------------------------------------------------------
__global__ __launch_bounds__(256) void gemm_fast3(
    const hb* __restrict__ Ah, const hb* __restrict__ Al,
    const hb* __restrict__ Bh, const hb* __restrict__ Bl,
    const float* __restrict__ bias, void* __restrict__ Cv, void* __restrict__ Cv2,
    int M, int N, int K, int lda, int ldb, int ldc, int act, int out_mode)
{
  const int bm = blockIdx.y * 128, bn = blockIdx.x * 128;
  const int tid = threadIdx.x;
  const int lane = tid & 63;
  const int wv = tid >> 6, wr = wv >> 1, wc = wv & 1;
  const int lrow = lane & 15, lk = lane >> 4;
  __shared__ __align__(16) hb AsH[128 * 64];
  __shared__ __align__(16) hb AsL[128 * 64];
  __shared__ __align__(16) hb BsH[128 * 64];
  __shared__ __align__(16) hb BsL[128 * 64];

  const int srow = tid >> 3;
  const int sc8 = tid & 7;
  const int sslot = (sc8 - srow) & 7;

  f32x4 acc[4][4];
#pragma unroll
  for (int mi = 0; mi < 4; ++mi)
#pragma unroll
    for (int ni = 0; ni < 4; ++ni) acc[mi][ni] = (f32x4){0.f, 0.f, 0.f, 0.f};

  long long aoff[4], boff[4];
#pragma unroll
  for (int it = 0; it < 4; ++it) {
    int gm = bm + srow + it * 32; if (gm > M - 1) gm = M - 1;
    int gn = bn + srow + it * 32; if (gn > N - 1) gn = N - 1;
    aoff[it] = (long long)gm * lda + sslot * 8;
    boff[it] = (long long)gn * ldb + sslot * 8;
  }

  for (int k0 = 0; k0 < K; k0 += 64) {
#pragma unroll
    for (int it = 0; it < 4; ++it) {
      gload16(Ah + aoff[it] + k0, &AsH[(tid + it * 256) * 8]);
      gload16(Al + aoff[it] + k0, &AsL[(tid + it * 256) * 8]);
      gload16(Bh + boff[it] + k0, &BsH[(tid + it * 256) * 8]);
      gload16(Bl + boff[it] + k0, &BsL[(tid + it * 256) * 8]);
    }
    __syncthreads();
#pragma unroll
    for (int ks = 0; ks < 2; ++ks) {
      const int sa = ((ks * 4 + lk + lrow) & 7) * 8;
      short8 aH[4], aL[4], bH[4], bL[4];
#pragma unroll
      for (int mi = 0; mi < 4; ++mi) {
        int r = (wr * 64 + mi * 16 + lrow) * 64 + sa;
        aH[mi] = *(const short8*)&AsH[r];
        aL[mi] = *(const short8*)&AsL[r];
      }
#pragma unroll
      for (int ni = 0; ni < 4; ++ni) {
        int r = (wc * 64 + ni * 16 + lrow) * 64 + sa;
        bH[ni] = *(const short8*)&BsH[r];
        bL[ni] = *(const short8*)&BsL[r];
      }
#pragma unroll
      for (int mi = 0; mi < 4; ++mi)
#pragma unroll
        for (int ni = 0; ni < 4; ++ni) {
          acc[mi][ni] = __builtin_amdgcn_mfma_f32_16x16x32_bf16(
              aH[mi], bH[ni], acc[mi][ni], 0, 0, 0);
          acc[mi][ni] = __builtin_amdgcn_mfma_f32_16x16x32_bf16(
              aL[mi], bH[ni], acc[mi][ni], 0, 0, 0);
          acc[mi][ni] = __builtin_amdgcn_mfma_f32_16x16x32_bf16(
              aH[mi], bL[ni], acc[mi][ni], 0, 0, 0);
        }
    }
    __syncthreads();
  }

  float* Cf = (float*)Cv;
  hb* Cb = (hb*)Cv;
  hb* Cb2 = (hb*)Cv2;
#pragma unroll
  for (int mi = 0; mi < 4; ++mi) {
#pragma unroll
    for (int ni = 0; ni < 4; ++ni) {
#pragma unroll
      for (int q = 0; q < 4; ++q) {
        int gm = bm + wr * 64 + mi * 16 + lk * 4 + q;
        int gn = bn + wc * 64 + ni * 16 + lrow;
        if (gm < M && gn < N) {
          float v = acc[mi][ni][q];
          if (bias) v += bias[gn];
          if (act)  v = gelu_f(v);
          long long off = (long long)gm * ldc + gn;
          if (out_mode == 2) {
            unsigned short h = bf_bits(v);
            unsigned short l = bf_bits(v - bf_back(h));
            Cb[off] = *reinterpret_cast<hb*>(&h);
            Cb2[off] = *reinterpret_cast<hb*>(&l);
          } else {
            Cf[off] = v;
          }
        }
      }
    }
  }
}

// ---------------------------------------------------------------------------
// Banded MFMA: partial[kq][b][s][d] = proj[s].em[s+d] over K-quarter (3-term)
// (term-major k-loop kept: accumulation ORDER preserves bitwise band values;
//  selection is order-sensitive — do not restructure)
// ---------------------------------------------------------------------------
__global__ __launch_bounds__(256) void bandmm(
    const hb* __restrict__ Phi, const hb* __restrict__ Plo,
    const hb* __restrict__ Ehi, const hb* __restrict__ Elo,
    float* __restrict__ partial)
{
  const int s0 = blockIdx.x * 64;
  const int kq = blockIdx.y;
  const int b = blockIdx.z;
  const int tid = threadIdx.x;
  const int lane = tid & 63;
  const int wv = tid >> 6, wr = wv >> 1, wc = wv & 1;
  const int lrow = lane & 15, lk = lane >> 4;
  __shared__ __align__(16) hb As[64 * 64];
  __shared__ __align__(16) hb Bs[96 * 64];

  f32x4 acc[2][3];
#pragma unroll
  for (int mi = 0; mi < 2; ++mi)
#pragma unroll
    for (int ni = 0; ni < 3; ++ni) acc[mi][ni] = (f32x4){0.f, 0.f, 0.f, 0.f};

  const long long Pbase = (long long)(b * S_LEN) * FDIM;
  long long aoff[2], boff[3];
#pragma unroll
  for (int it = 0; it < 2; ++it) {
    int row = (tid + it * 256) >> 3;
    aoff[it] = Pbase + (long long)(s0 + row) * FDIM + (tid & 7) * 8;
  }
#pragma unroll
  for (int it = 0; it < 3; ++it) {
    int row = (tid + it * 256) >> 3;
    int t = s0 + row; if (t > S_LEN - 1) t = S_LEN - 1;
    boff[it] = Pbase + (long long)t * FDIM + (tid & 7) * 8;
  }

  const int kbeg = kq * (FDIM / 4), kend = kbeg + FDIM / 4;
  for (int t3 = 0; t3 < 3; ++t3) {
    const hb* Ap = (t3 == 1) ? Plo : Phi;
    const hb* Bp = (t3 == 2) ? Elo : Ehi;
    for (int k0 = kbeg; k0 < kend; k0 += 64) {
#pragma unroll
      for (int it = 0; it < 2; ++it)
        gload16(Ap + aoff[it] + k0, &As[(tid + it * 256) * 8]);
#pragma unroll
      for (int it = 0; it < 3; ++it)
        gload16(Bp + boff[it] + k0, &Bs[(tid + it * 256) * 8]);
      __syncthreads();
#pragma unroll
      for (int ks = 0; ks < 2; ++ks) {
        short8 a[2], bb[3];
#pragma unroll
        for (int mi = 0; mi < 2; ++mi)
          a[mi] = *(const short8*)&As[(wr * 32 + mi * 16 + lrow) * 64 + ks * 32 + lk * 8];
#pragma unroll
        for (int ni = 0; ni < 3; ++ni)
          bb[ni] = *(const short8*)&Bs[(wc * 48 + ni * 16 + lrow) * 64 + ks * 32 + lk * 8];
#pragma unroll
        for (int mi = 0; mi < 2; ++mi)
#pragma unroll
          for (int ni = 0; ni < 3; ++ni)
            acc[mi][ni] = __builtin_amdgcn_mfma_f32_16x16x32_bf16(
                a[mi], bb[ni], acc[mi][ni], 0, 0, 0);
      }
      __syncthreads();
    }
  }

#pragma unroll
  for (int mi = 0; mi < 2; ++mi) {
#pragma unroll
    for (int ni = 0; ni < 3; ++ni) {
#pragma unroll
      for (int q = 0; q < 4; ++q) {
        int i = wr * 32 + mi * 16 + lk * 4 + q;
        int n = wc * 48 + ni * 16 + lrow;
        int d = n - i;
        if (d >= 0 && d < 32) {
          long long off = (((long long)(kq * 2 + b)) * S_LEN + (s0 + i)) * 32 + d;
          partial[off] = acc[mi][ni][q];
        }
      }
    }
  }
}

// ---------------------------------------------------------------------------
// Merged prep: split emb f32 -> hi/lo bf16 (first nb_split blocks) AND
// split+transpose W f32 [K][N] -> hiT/loT bf16 [N][K] (remaining blocks).
// W path uses 64k x 32n tiles with packed uint stores (128B write segments).
// nb_T host-side = (N/32)*(K/64).
// ---------------------------------------------------------------------------
__global__ __launch_bounds__(256) void prep_split(
    const float* __restrict__ emb, hb* __restrict__ hi, hb* __restrict__ lo,
    long long n4, int nb_split,
    const float* __restrict__ W, hb* __restrict__ WhiT, hb* __restrict__ WloT,
    int K, int N)
{
  if ((int)blockIdx.x < nb_split) {
    long long i = (long long)blockIdx.x * 256 + threadIdx.x;
    if (i >= n4) return;
    float4 v = ((const float4*)emb)[i];
    unsigned short h[4], l[4];
    float vv[4] = {v.x, v.y, v.z, v.w};
#pragma unroll
    for (int j = 0; j < 4; ++j) {
      h[j] = bf_bits(vv[j]);
      l[j] = bf_bits(vv[j] - bf_back(h[j]));
    }
    ((uint2*)hi)[i] = *(uint2*)h;
    ((uint2*)lo)[i] = *(uint2*)l;
    return;
  }
  __shared__ float t[64][33];
  int idx = blockIdx.x - nb_split;
  int nbx = N / 32;
  int xb = idx % nbx, yb = idx / nbx;
  int k0 = yb * 64, n0 = xb * 32;
  if (k0 >= K) return;
  int tx = threadIdx.x & 31, ty = threadIdx.x >> 5;
#pragma unroll
  for (int r = 0; r < 8; ++r)
    t[ty + r * 8][tx] = W[(long long)(k0 + ty + r * 8) * N + (n0 + tx)];
  __syncthreads();
#pragma unroll
  for (int r = 0; r < 4; ++r) {
    int n = n0 + ty + r * 8;
    float v0 = t[tx * 2][ty + r * 8];
    float v1 = t[tx * 2 + 1][ty + r * 8];
    unsigned short h0 = bf_bits(v0), h1 = bf_bits(v1);
    unsigned short l0 = bf_bits(v0 - bf_back(h0));
    unsigned short l1 = bf_bits(v1 - bf_back(h1));
    ((unsigned*)(WhiT + (long long)n * K + k0))[tx] =
        (unsigned)h0 | ((unsigned)h1 << 16);
    ((unsigned*)(WloT + (long long)n * K + k0))[tx] =
        (unsigned)l0 | ((unsigned)l1 << 16);
  }
}

// split + transpose only (s2e_W, FDIM x FDIM), 64k x 32n tiles
__global__ __launch_bounds__(256) void splitT_mat(
    const float* __restrict__ src, hb* __restrict__ hiT, hb* __restrict__ loT,
    int K, int N)
{
  __shared__ float t[64][33];
  int k0 = blockIdx.y * 64, n0 = blockIdx.x * 32;
  int tx = threadIdx.x & 31, ty = threadIdx.x >> 5;
#pragma unroll
  for (int r = 0; r < 8; ++r)
    t[ty + r * 8][tx] = src[(long long)(k0 + ty + r * 8) * N + (n0 + tx)];
  __syncthreads();
#pragma unroll
  for (int r = 0; r < 4; ++r) {
    int n = n0 + ty + r * 8;
    float v0 = t[tx * 2][ty + r * 8];
    float v1 = t[tx * 2 + 1][ty + r * 8];
    unsigned short h0 = bf_bits(v0), h1 = bf_bits(v1);
    unsigned short l0 = bf_bits(v0 - bf_back(h0));
    unsigned short l1 = bf_bits(v1 - bf_back(h1));
    ((unsigned*)(hiT + (long long)n * K + k0))[tx] =
        (unsigned)h0 | ((unsigned)h1 << 16);
    ((unsigned*)(loT + (long long)n * K + k0))[tx] =
        (unsigned)l0 | ((unsigned)l1 << 16);
  }
}

// ---------------------------------------------------------------------------
// Fused LayerNorm (fp64 stats) + hi/lo bf16 split + cls row-dot (fp64 accum)
// ---------------------------------------------------------------------------
__global__ __launch_bounds__(256) void ln_split_dot(
    const float* __restrict__ src, hb* __restrict__ hi, hb* __restrict__ lo,
    const float* __restrict__ g, const float* __restrict__ be,
    const float* __restrict__ w, const float* __restrict__ wb,
    float* __restrict__ dot_out)
{
  __shared__ float row[FDIM];
  __shared__ double scr[4];
  __shared__ double sh_mu, sh_rstd;
  const long long r = blockIdx.x;
  const float* p = src + r * FDIM;
  const int tid = threadIdx.x;

  double s = 0.0;
#pragma unroll
  for (int pp = 0; pp < 3; ++pp) {
    int c4 = pp * 256 + tid;
    float4 v = *(const float4*)(p + c4 * 4);
    *(float4*)&row[c4 * 4] = v;
    s += (double)v.x + (double)v.y + (double)v.z + (double)v.w;
  }
#pragma unroll
  for (int off = 32; off; off >>= 1) s += __shfl_down(s, off, 64);
  if ((tid & 63) == 0) scr[tid >> 6] = s;
  __syncthreads();
  if (tid == 0) sh_mu = (scr[0] + scr[1] + scr[2] + scr[3]) / FDIM;
  __syncthreads();
  double mu = sh_mu;
  double vs = 0.0;
#pragma unroll
  for (int pp = 0; pp < 12; ++pp) {
    double d = (double)row[pp * 256 + tid] - mu;
    vs += d * d;
  }
#pragma unroll
  for (int off = 32; off; off >>= 1) vs += __shfl_down(vs, off, 64);
  __syncthreads();
  if ((tid & 63) == 0) scr[tid >> 6] = vs;
  __syncthreads();
  if (tid == 0)
    sh_rstd = 1.0 / sqrt((scr[0] + scr[1] + scr[2] + scr[3]) / FDIM + 1e-5);
  __syncthreads();
  double rstd = sh_rstd;

  double dot = 0.0;
#pragma unroll
  for (int pp = 0; pp < 3; ++pp) {
    int c4 = pp * 256 + tid;
    float4 gv = *(const float4*)(g + c4 * 4);
    float4 bv = *(const float4*)(be + c4 * 4);
    float4 wv = *(const float4*)(w + c4 * 4);
    float xv[4];
    *(float4*)xv = *(const float4*)&row[c4 * 4];
    unsigned short hh[4], ll[4];
    float gg[4] = {gv.x, gv.y, gv.z, gv.w};
    float bb[4] = {bv.x, bv.y, bv.z, bv.w};
    float ww[4] = {wv.x, wv.y, wv.z, wv.w};
#pragma unroll
    for (int j = 0; j < 4; ++j) {
      float val = (float)(((double)xv[j] - mu) * rstd * (double)gg[j] + (double)bb[j]);
      dot += (double)val * (double)ww[j];
      hh[j] = bf_bits(val);
      ll[j] = bf_bits(val - bf_back(hh[j]));
    }
    *(uint2*)(hi + r * FDIM + c4 * 4) = *(uint2*)hh;
    *(uint2*)(lo + r * FDIM + c4 * 4) = *(uint2*)ll;
  }
#pragma unroll
  for (int off = 32; off; off >>= 1) dot += __shfl_down(dot, off, 64);
  __syncthreads();
  if ((tid & 63) == 0) scr[tid >> 6] = dot;
  __syncthreads();
  if (tid == 0)
    dot_out[r] = (float)(scr[0] + scr[1] + scr[2] + scr[3] + (double)wb[0]);
}

// LayerNorm f32 src -> bf16 dst, y-batched pair (phase-2)
__global__ __launch_bounds__(256) void ln_rows_bf2(
    const float* __restrict__ src0, const float* __restrict__ src1,
    hb* __restrict__ dst0, hb* __restrict__ dst1,
    const float* __restrict__ g0, const float* __restrict__ g1,
    const float* __restrict__ be0, const float* __restrict__ be1,
    int n, long long lds_, long long ldd)
{
  const int sel = blockIdx.y;
  long long r = blockIdx.x;
  const float* p = (sel ? src1 : src0) + r * lds_;
  hb* d = (sel ? dst1 : dst0) + r * ldd;
  const float* g = sel ? g1 : g0;
  const float* be = sel ? be1 : be0;
  __shared__ double scratch[4];
  __shared__ double sh_mu, sh_rstd;
  double s = 0.0;
  for (int c = threadIdx.x; c < n; c += 256) s += (double)p[c];
#pragma unroll
  for (int off = 32; off; off >>= 1) s += __shfl_down(s, off, 64);
  if ((threadIdx.x & 63) == 0) scratch[threadIdx.x >> 6] = s;
  __syncthreads();
  if (threadIdx.x == 0) sh_mu = (scratch[0] + scratch[1] + scratch[2] + scratch[3]) / n;
  __syncthreads();
  double mu = sh_mu;
  double vs = 0.0;
  for (int c = threadIdx.x; c < n; c += 256) { double dd = (double)p[c] - mu; vs += dd * dd; }
#pragma unroll
  for (int off = 32; off; off >>= 1) vs += __shfl_down(vs, off, 64);
  __syncthreads();
  if ((threadIdx.x & 63) == 0) scratch[threadIdx.x >> 6] = vs;
  __syncthreads();
  if (threadIdx.x == 0)
    sh_rstd = 1.0 / sqrt((scratch[0] + scratch[1] + scratch[2] + scratch[3]) / n + 1e-5);
  __syncthreads();
  double rstd = sh_rstd;
  for (int c = threadIdx.x; c < n; c += 256)
    d[c] = __float2bfloat16(
        (float)(((double)p[c] - mu) * rstd * (double)g[c] + (double)be[c]));
}

// ---------------------------------------------------------------------------
// Top-k selection, 1 block/batch, with band computation FUSED in front
// (same partial-sum order as the old band_reduce — bitwise identical band).
// Scans are LINEAR over the padded [S_LEN][32] slab (float4, coalesced).
// Pad columns hold -3e38: keys strictly below any clipped in-band value,
// and kv <= 819 << 61005 real entries, so pads can never be selected.
// ---------------------------------------------------------------------------
__device__ __forceinline__ unsigned f2k(float f) {
  unsigned u = __float_as_uint(f);
  return (u & 0x80000000u) ? ~u : (u | 0x80000000u);
}

__device__ void bitonic1024(int* a) {
  const int tid = threadIdx.x;
  for (int sz = 2; sz <= 1024; sz <<= 1) {
    for (int st = sz >> 1; st > 0; st >>= 1) {
      __syncthreads();
      int j = tid ^ st;
      if (j > tid) {
        int x = a[tid], y = a[j];
        bool asc = (tid & sz) == 0;
        if ((x > y) == asc) { a[tid] = y; a[j] = x; }
      }
    }
  }
  __syncthreads();
}

__global__ __launch_bounds__(1024) void select_sort(
    const float* __restrict__ partial, const float* __restrict__ ssc,
    const float* __restrict__ esc, float* __restrict__ band,
    const int* __restrict__ masks,
    int* __restrict__ sidx, int* __restrict__ starts, int* __restrict__ ends,
    float* __restrict__ tms, int* __restrict__ kvals)
{
  const int b = blockIdx.x;
  const int tid = threadIdx.x;
  __shared__ int hist[256];
  __shared__ int sel[1024];
  __shared__ int eq[1024];
  __shared__ int sred[16];
  __shared__ int cvar[4];
  __shared__ int cnt_gt, cnt_eq;

  // ---- fused band_reduce (verbatim formula/order of the old kernel) ----
  float* bw = band + (long long)b * (S_LEN * 32);
  for (int idx = tid; idx < S_LEN * 32; idx += 1024) {
    int d = idx & 31;
    int s = idx >> 5;
    int tt = s + d;
    float v;
    if (d < MAXSPAN && tt < S_LEN) {
      float sum = 0.f;
#pragma unroll
      for (int kq = 0; kq < 4; ++kq)
        sum += partial[(((long long)(kq * 2 + b)) * S_LEN + s) * 32 + d];
      sum += ssc[b * S_LEN + s] + esc[b * S_LEN + tt];
      v = fminf(fmaxf(sum, NEGV), -NEGV);
    } else {
      v = -3.0e38f;
    }
    bw[idx] = v;
  }
  __syncthreads();   // block-wide: global writes above visible to reads below

  int msum = 0;
  for (int i = tid; i < S_LEN; i += 1024) msum += masks[b * S_LEN + i];
#pragma unroll
  for (int off = 32; off; off >>= 1) msum += __shfl_down(msum, off, 64);
  if ((tid & 63) == 0) sred[tid >> 6] = msum;
  __syncthreads();
  if (tid == 0) {
    int t = 0;
    for (int w = 0; w < 16; ++w) t += sred[w];
    cvar[2] = t;
  }
  __syncthreads();
  int kv = (int)((float)cvar[2] * 0.4f);
  if (kv > MAXK) kv = MAXK;
  if (kv < 0) kv = 0;

  const float4* b4 = (const float4*)bw;
  const int N4 = S_LEN * 8;            // 16384 float4 covering padded slab
  unsigned prefix = 0u;
  int remaining = kv;

  if (kv > 0) {
    for (int byte = 3; byte >= 0; --byte) {
      if (tid < 256) hist[tid] = 0;
      __syncthreads();
      for (int i = tid; i < N4; i += 1024) {
        float4 v = b4[i];
        float vv[4] = {v.x, v.y, v.z, v.w};
#pragma unroll
        for (int j = 0; j < 4; ++j) {
          unsigned key = f2k(vv[j]);
          bool match = (byte == 3) ||
              ((key >> ((byte + 1) * 8)) == (prefix >> ((byte + 1) * 8)));
          if (match) atomicAdd(&hist[(key >> (byte * 8)) & 255], 1);
        }
      }
      __syncthreads();
      if (tid == 0) {
        int cum = 0, chosen = 255;
        for (int v = 255; v >= 0; --v) {
          int h = hist[v];
          if (cum + h >= remaining) { chosen = v; cvar[0] = remaining - cum; break; }
          cum += h;
        }
        cvar[1] = chosen;
      }
      __syncthreads();
      remaining = cvar[0];
      prefix |= ((unsigned)cvar[1]) << (byte * 8);
      __syncthreads();
    }
    if (tid == 0) { cnt_gt = 0; cnt_eq = 0; }
    __syncthreads();
    for (int i = tid; i < N4; i += 1024) {
      float4 v = b4[i];
      float vv[4] = {v.x, v.y, v.z, v.w};
#pragma unroll
      for (int j = 0; j < 4; ++j) {
        unsigned key = f2k(vv[j]);
        if (key < prefix) continue;
        int e = i * 4 + j;
        int s = e >> 5, d = e & 31;
        int flat = s * S_LEN + s + d;
        if (key > prefix) {
          int p = atomicAdd(&cnt_gt, 1);
          if (p < MAXK) sel[p] = flat;
        } else {
          int p = atomicAdd(&cnt_eq, 1);
          if (p < 1024) eq[p] = flat;
        }
      }
    }
    __syncthreads();
    int ngt = cnt_gt;
    int neq = cnt_eq; if (neq > 1024) neq = 1024;
    if (tid >= neq) eq[tid] = 0x7FFFFFFF;
    __syncthreads();
    bitonic1024(eq);
    int need = kv - ngt;
    if (tid < need) sel[ngt + tid] = eq[tid];
    __syncthreads();
  }
  if (tid >= kv && tid < MAXK) sel[tid] = S_LEN * S_LEN - 1;
  if (tid >= MAXK) sel[tid] = 0x7FFFFFFF;
  __syncthreads();
  bitonic1024(sel);
  if (tid < MAXK) {
    int idx = sel[tid];
    int s = idx >> 11;
    int t = idx & (S_LEN - 1);
    sidx[b * MAXK + tid] = idx;
    starts[b * MAXK + tid] = s;
    ends[b * MAXK + tid] = t;
    tms[b * MAXK + tid] = band[((long long)(b * S_LEN + s)) * 32 + (t - s)];
  }
  if (tid == 0) kvals[b] = kv;
}

// ---------------------------------------------------------------------------
// Merged phase-2 weight prep + gather, one node. grid (96, 48, 6):
//  z in 0..3, y<48 : transpose+convert a_{ss,es,se,ee}_W -> Wq1t/Wq2t cat
//                    (64k x 32n tiles, packed uint stores)
//  z == 4, y<16    : transpose+convert sc_W -> scWt
//  z == 4, 16<=y<32: transpose+convert ec_W -> ecWt
//  z == 4, y==32, x<24 : biasq cat = [a_ss_b+a_es_b | a_se_b+a_ee_b]
//  z == 5, u=y*96+x<3276 : gather rows (u<1638: starts->Xs, else ends->Xe)
// ---------------------------------------------------------------------------
__global__ __launch_bounds__(256) void wprep(
    const float* __restrict__ a0W, const float* __restrict__ a1W,
    const float* __restrict__ a2W, const float* __restrict__ a3W,
    hb* __restrict__ Wq1t, hb* __restrict__ Wq2t,
    const float* __restrict__ scW, const float* __restrict__ ecW,
    hb* __restrict__ scWt, hb* __restrict__ ecWt,
    const float* __restrict__ b0, const float* __restrict__ b1,
    const float* __restrict__ b2, const float* __restrict__ b3,
    float* __restrict__ biasq,
    const float* __restrict__ emb,
    const int* __restrict__ starts, const int* __restrict__ ends,
    hb* __restrict__ Xs, hb* __restrict__ Xe)
{
  __shared__ float t[64][33];
  const int z = blockIdx.z;
  int tx = threadIdx.x & 31, ty = threadIdx.x >> 5;
  if (z < 4) {
    if ((int)blockIdx.y >= FDIM / 64) return;   // defensive
    const float* src = (z == 0) ? a0W : (z == 1) ? a1W : (z == 2) ? a2W : a3W;
    hb* dst = (z < 2) ? Wq1t : Wq2t;
    const int koff = (z & 1) * FDIM;
    int k0 = blockIdx.y * 64, n0 = blockIdx.x * 32;
#pragma unroll
    for (int r = 0; r < 8; ++r)
      t[ty + r * 8][tx] = src[(long long)(k0 + ty + r * 8) * FDIM + (n0 + tx)];
    __syncthreads();
#pragma unroll
    for (int r = 0; r < 4; ++r) {
      int n = n0 + ty + r * 8;
      float v0 = t[tx * 2][ty + r * 8];
      float v1 = t[tx * 2 + 1][ty + r * 8];
      ((unsigned*)(dst + (long long)n * (2 * FDIM) + koff + k0))[tx] =
          (unsigned)bf_bits(v0) | ((unsigned)bf_bits(v1) << 16);
    }
  } else if (z == 4) {
    int yy = blockIdx.y;
    if (yy < 32) {
      const float* src = (yy < 16) ? scW : ecW;
      hb* dst = (yy < 16) ? scWt : ecWt;
      int k0 = (yy & 15) * 64, n0 = blockIdx.x * 32;
#pragma unroll
      for (int r = 0; r < 8; ++r)
        t[ty + r * 8][tx] = src[(long long)(k0 + ty + r * 8) * FDIM + (n0 + tx)];
      __syncthreads();
#pragma unroll
      for (int r = 0; r < 4; ++r) {
        int n = n0 + ty + r * 8;
        float v0 = t[tx * 2][ty + r * 8];
        float v1 = t[tx * 2 + 1][ty + r * 8];
        ((unsigned*)(dst + (long long)n * HDIM + k0))[tx] =
            (unsigned)bf_bits(v0) | ((unsigned)bf_bits(v1) << 16);
      }
    } else if (yy == 32 && blockIdx.x < 24) {
      int i = blockIdx.x * 256 + threadIdx.x;   // 0..6143
      if (i < FDIM) biasq[i] = b0[i] + b1[i];
      else          biasq[i] = b2[i - FDIM] + b3[i - FDIM];
    }
  } else {
    const int MR = BATCH * MAXK;                // 1638
    int u = blockIdx.y * (FDIM / 32) + blockIdx.x;
    if (u >= 2 * MR) return;
    int which = u >= MR;
    int g = u - which * MR;
    int b = g / MAXK;
    const int* rows = which ? ends : starts;
    hb* dst = which ? Xe : Xs;
    int r = rows[g];
    float4 v = ((const float4*)(emb + ((long long)(b * S_LEN + r)) * HDIM))[threadIdx.x];
    unsigned plo = (unsigned)bf_bits(v.x) | ((unsigned)bf_bits(v.y) << 16);
    unsigned phi = (unsigned)bf_bits(v.z) | ((unsigned)bf_bits(v.w) << 16);
    uint2 pk; pk.x = plo; pk.y = phi;
    ((uint2*)(dst + (long long)g * HDIM))[threadIdx.x] = pk;
  }
}

// out[b,i,j] assembly: sum 4 coref K-slices + pair + anaphora mask, zero last col
__global__ __launch_bounds__(256) void final_assemble(
    const float* __restrict__ coref4, const float* __restrict__ tms,
    const int* __restrict__ kvals, float* __restrict__ out)
{
  const long long SL = (long long)MAXK * MAXK;   // slice stride
  int g = blockIdx.x;                   // b*MAXK + i
  int b = g / MAXK;
  int i = g - b * MAXK;
  int kv = kvals[b];
  float ti = tms[g];
  const float* crow = coref4 + (long long)(b * 4) * SL + (long long)i * MAXK;
  float* orow = out + (long long)b * MAXK * (MAXK + 1) + (long long)i * (MAXK + 1);
  for (int j = threadIdx.x; j < MAXK + 1; j += 256) {
    float v;
    if (j == MAXK) v = 0.f;
    else {
      float c = ((crow[j] + crow[j + SL]) + (crow[j + 2 * SL] + crow[j + 3 * SL]));
      v = ti + tms[b * MAXK + j] + c;
      if (!((j < i) && (i < kv))) v += NEGV;
      v = fminf(fmaxf(v, NEGV), -NEGV);
    }
    orow[j] = v;
  }
}

// ---------------------------------------------------------------------------
static inline void launch1(const hb* A, const hb* B,
    const float* bias, const float* bias2, void* C,
    int M, int N, int K, int lda, int ldb, int ldc,
    long long sA, long long sB, long long sC,
    int act, int out_mode, int zcount, int kspl, hipStream_t stream)
{
  dim3 grid((N + 127) / 128, (M + 127) / 128, zcount);
  gemm_fast1<<<grid, 256, 0, stream>>>(A, B, bias, bias2, C, M, N, K,
                                       lda, ldb, ldc, sA, sB, sC,
                                       act, out_mode, kspl);
}

static inline void launch3(const hb* Ah, const hb* Al, const hb* Bh, const hb* Bl,
    const float* bias, void* C, void* C2, int M, int N, int K,
    int lda, int ldb, int ldc, int act, int out_mode, hipStream_t stream)
{
  dim3 grid((N + 127) / 128, (M + 127) / 128, 1);
  gemm_fast3<<<grid, 256, 0, stream>>>(Ah, Al, Bh, Bl, bias, C, C2,
                                       M, N, K, lda, ldb, ldc, act, out_mode);
}

extern "C" void kernel_launch(void* const* d_in, const int* in_sizes, int n_in,
                              void* d_out, int out_size, void* d_ws, size_t ws_size,
                              hipStream_t stream) {
  const float* input_emb = (const float*)d_in[0];
  const int*   input_masks = (const int*)d_in[1];
  const float* sm_W = (const float*)d_in[2];
  const float* sm_b = (const float*)d_in[3];
  const float* sm_g = (const float*)d_in[4];
  const float* sm_be = (const float*)d_in[5];
  const float* em_W = (const float*)d_in[6];
  const float* em_b = (const float*)d_in[7];
  const float* em_g = (const float*)d_in[8];
  const float* em_be = (const float*)d_in[9];
  const float* sc_W = (const float*)d_in[10];
  const float* sc_b = (const float*)d_in[11];
  const float* sc_g = (const float*)d_in[12];
  const float* sc_be = (const float*)d_in[13];
  const float* ec_W = (const float*)d_in[14];
  const float* ec_b = (const float*)d_in[15];
  const float* ec_g = (const float*)d_in[16];
  const float* ec_be = (const float*)d_in[17];
  const float* cls_s_W = (const float*)d_in[18];
  const float* cls_s_b = (const float*)d_in[19];
  const float* cls_e_W = (const float*)d_in[20];
  const float* cls_e_b = (const float*)d_in[21];
  const float* s2e_W = (const float*)d_in[22];
  const float* s2e_b = (const float*)d_in[23];
  const float* a_ss_W = (const float*)d_in[24];
  const float* a_ss_b = (const float*)d_in[25];
  const float* a_ee_W = (const float*)d_in[26];
  const float* a_ee_b = (const float*)d_in[27];
  const float* a_se_W = (const float*)d_in[28];
  const float* a_se_b = (const float*)d_in[29];
  const float* a_es_W = (const float*)d_in[30];
  const float* a_es_b = (const float*)d_in[31];
  float* out = (float*)d_out;

  const int NROW = BATCH * S_LEN;           // 4096
  const int MROW = BATCH * MAXK;            // 1638
  const long long SZ_BIG = (long long)NROW * FDIM * 4;      // 50331648

  char* ws = (char*)d_ws;
  // ---- phase-1 regions (schedule in launch order) ----
  float* smF    = (float*)(ws);                     // sm f32, dead after LN
  hb* sm_hi     = (hb*)(ws + 50331648LL);
  hb* sm_lo     = (hb*)(ws + 75497472LL);
  hb* emb_hi    = (hb*)(ws + 100663296LL);
  hb* emb_lo    = (hb*)(ws + 109051904LL);
  hb* w1_hiT    = (hb*)(ws + 117440512LL);
  hb* w1_loT    = (hb*)(ws + 123731968LL);
  hb* s2e_hiT   = (hb*)(ws);                        // after smF dead
  hb* s2e_loT   = (hb*)(ws + 18874368LL);
  hb* proj_hi   = (hb*)(ws + 100663296LL);          // after emb/w1 dead
  hb* proj_lo   = (hb*)(ws + 125829120LL);
  hb* emb2_hi   = (hb*)(ws);                        // after s2eT dead
  hb* emb2_lo   = (hb*)(ws + 8388608LL);
  hb* w2_hiT    = (hb*)(ws + 16777216LL);
  hb* w2_loT    = (hb*)(ws + 23068672LL);
  float* emF    = (float*)(ws + 50331648LL);        // after sm splits dead
  hb* em_hi     = (hb*)(ws);                        // after emb2/w2 dead
  hb* em_lo     = (hb*)(ws + 25165824LL);
  float* partial = (float*)(ws + 50331648LL);       // after emF dead, 2 MB
  // ---- phase-2 overlay (all weights coexist -> 1 wprep node) ----
  hb* Wq1t  = (hb*)(ws);                            // [3072][6144] cat rows 0..3071
  hb* Wq2t  = (hb*)(ws + 37748736LL);               // rows 3072..6143 (contig!)
  hb* tkcat = (hb*)(ws + 75497472LL);               // [1638][6144]
  hb* qcat  = (hb*)(ws + 95625216LL);               // live after mlp dead
  float* coref4 = (float*)(ws + 115752960LL);       // [2][4][819][819] f32
  float* mlp_s = (float*)(ws + 95625216LL);         // overlays future qcat
  float* mlp_e = (float*)(ws + 115752960LL);        // overlays future coref4
  hb* Xs_bf = (hb*)(ws + 75497472LL);               // inside future tkcat
  hb* Xe_bf = (hb*)(ws + 78852096LL);               //   (dead before tkcat write)
  hb* scWt  = (hb*)(ws + 82206720LL);
  hb* ecWt  = (hb*)(ws + 88498176LL);
  // ---- persistent tail ----
  const long long P = 3 * SZ_BIG;                   // 150994944
  float* band = (float*)(ws + P);
  float* ssc  = (float*)(ws + P + 524288);
  float* esc  = (float*)(ws + P + 540672);
  int* sidx   = (int*)(ws + P + 557056);
  int* starts = (int*)(ws + P + 565248);
  int* ends   = (int*)(ws + P + 573440);
  float* tms  = (float*)(ws + P + 581632);
  int* kvals  = (int*)(ws + P + 589824);
  float* biasq1 = (float*)(ws + P + 590080);        // [3072]
  float* biasq2 = (float*)(ws + P + 602368);        // contiguous -> [6144] cat
  (void)biasq2;
  if (ws_size < (size_t)(P + 614656)) return;

  const long long n4_emb = (long long)NROW * HDIM / 4;
  const int nb_split = (int)((n4_emb + 255) / 256);
  const int nb_T = (FDIM / 32) * (HDIM / 64);       // 64k x 32n tiles

  // ---- phase 1: selection-critical chain ----
  prep_split<<<nb_split + nb_T, 256, 0, stream>>>(
      input_emb, emb_hi, emb_lo, n4_emb, nb_split, sm_W, w1_hiT, w1_loT, HDIM, FDIM);
  launch3(emb_hi, emb_lo, w1_hiT, w1_loT, sm_b, smF, nullptr,
          NROW, FDIM, HDIM, HDIM, HDIM, FDIM, 1, 0, stream);
  ln_split_dot<<<NROW, 256, 0, stream>>>(smF, sm_hi, sm_lo, sm_g, sm_be,
                                         cls_s_W, cls_s_b, ssc);
  splitT_mat<<<dim3(FDIM / 32, FDIM / 64), 256, 0, stream>>>(s2e_W, s2e_hiT, s2e_loT, FDIM, FDIM);
  launch3(sm_hi, sm_lo, s2e_hiT, s2e_loT, s2e_b, proj_hi, proj_lo,
          NROW, FDIM, FDIM, FDIM, FDIM, FDIM, 0, 2, stream);
  prep_split<<<nb_split + nb_T, 256, 0, stream>>>(
      input_emb, emb2_hi, emb2_lo, n4_emb, nb_split, em_W, w2_hiT, w2_loT, HDIM, FDIM);
  launch3(emb2_hi, emb2_lo, w2_hiT, w2_loT, em_b, emF, nullptr,
          NROW, FDIM, HDIM, HDIM, HDIM, FDIM, 1, 0, stream);
  ln_split_dot<<<NROW, 256, 0, stream>>>(emF, em_hi, em_lo, em_g, em_be,
                                         cls_e_W, cls_e_b, esc);
  bandmm<<<dim3(S_LEN / 64, 4, BATCH), 256, 0, stream>>>(proj_hi, proj_lo, em_hi, em_lo, partial);
  select_sort<<<BATCH, 1024, 0, stream>>>(partial, ssc, esc, band, input_masks,
                                          sidx, starts, ends, tms, kvals);

  // ---- phase 2 ----
  wprep<<<dim3(FDIM / 32, FDIM / 64, 6), 256, 0, stream>>>(
      a_ss_W, a_es_W, a_se_W, a_ee_W, Wq1t, Wq2t,
      sc_W, ec_W, scWt, ecWt,
      a_ss_b, a_es_b, a_se_b, a_ee_b, biasq1,
      input_emb, starts, ends, Xs_bf, Xe_bf);

  // batched mlp_s/mlp_e: z=2, contiguous operand strides, per-z bias
  launch1(Xs_bf, scWt, sc_b, ec_b, mlp_s, MROW, FDIM, HDIM, HDIM, HDIM, FDIM,
          (long long)MROW * HDIM, (long long)FDIM * HDIM, (long long)MROW * FDIM,
          1, 0, 2, 1, stream);

  ln_rows_bf2<<<dim3(MROW, 2), 256, 0, stream>>>(
      mlp_s, mlp_e, tkcat, tkcat + FDIM, sc_g, ec_g, sc_be, ec_be,
      FDIM, FDIM, 2 * FDIM);

  // fused qcat: N = 6144 over contiguous [Wq1t; Wq2t] and [biasq1|biasq2]
  launch1(tkcat, Wq1t, biasq1, nullptr, qcat, MROW, 2 * FDIM, 2 * FDIM,
          2 * FDIM, 2 * FDIM, 2 * FDIM, 0, 0, 0, 0, 1, 1, 1, stream);

  // coref: split-K x4 (K=1536/slice), batched z = b*4 + ks
  launch1(qcat, tkcat, nullptr, nullptr, coref4, MAXK, MAXK, 1536,
          2 * FDIM, 2 * FDIM, MAXK,
          (long long)MAXK * 2 * FDIM, (long long)MAXK * 2 * FDIM,
          (long long)MAXK * MAXK, 0, 0, BATCH * 4, 4, stream);

  final_assemble<<<MROW, 256, 0, stream>>>(coref4, tms, kvals, out);
}

// Round 7
// 1203.772 us; speedup vs baseline: 1.0244x; 1.0244x over previous
//
#include <hip/hip_runtime.h>
#include <hip/hip_bf16.h>
#include <math.h>

#define S_LEN 2048
#define BATCH 2
#define HDIM 1024
#define FDIM 3072
#define MAXK 819
#define MAXSPAN 30
#define NEGV -10000.0f

typedef __attribute__((ext_vector_type(8))) short short8;
typedef __attribute__((ext_vector_type(4))) float f32x4;
typedef __hip_bfloat16 hb;

__device__ __forceinline__ float gelu_f(float x) {
  return 0.5f * x * (1.0f + erff(x * 0.70710678118654752440f));
}

__device__ __forceinline__ unsigned short bf_bits(float x) {
  hb b = __float2bfloat16(x);
  return *reinterpret_cast<unsigned short*>(&b);
}
__device__ __forceinline__ float bf_back(unsigned short u) {
  hb b = *reinterpret_cast<hb*>(&u);
  return __bfloat162float(b);
}

__device__ __forceinline__ void gload16(const void* g, void* l) {
  __builtin_amdgcn_global_load_lds(
      (const __attribute__((address_space(1))) void*)g,
      (__attribute__((address_space(3))) void*)l, 16, 0, 0);
}

// ---------------------------------------------------------------------------
// bf16 MFMA GEMM, single-term, BK=128 (128 MFMA per barrier-pair).
// C[M,N] = act(A[M,K] @ B[N,K]^T + bias).  K multiple of 128.
// z-batching: blockIdx.z = zb*kspl + zk; operands at zb*sA/sB, k-slice zk,
// C slice at blockIdx.z * sC.  bias2 (if non-null) replaces bias for zb>=1.
// NOTE: XCD-chunked blockIdx remap was tried (r1/r2) and REGRESSED here:
// inputs are L3-resident and kernel is not HBM-bound; chunking de-correlates
// the XCDs' B-panel streams (FETCH 240->326 MB). Keep default dispatch order.
// ---------------------------------------------------------------------------
__global__ __launch_bounds__(256) void gemm_fast1(
    const hb* __restrict__ A, const hb* __restrict__ B,
    const float* __restrict__ bias, const float* __restrict__ bias2,
    void* __restrict__ Cv,
    int M, int N, int K, int lda, int ldb, int ldc,
    long long sA, long long sB, long long sC,
    int act, int out_mode, int kspl)
{
  const int zb = blockIdx.z / kspl, zk = blockIdx.z - zb * kspl;
  A += (long long)zb * sA + (long long)zk * K;
  B += (long long)zb * sB + (long long)zk * K;
  const long long cbase = (long long)blockIdx.z * sC;
  const float* bp = (bias2 && zb) ? bias2 : bias;
  const int bm = blockIdx.y * 128, bn = blockIdx.x * 128;
  const int tid = threadIdx.x;
  const int lane = tid & 63;
  const int wv = tid >> 6, wr = wv >> 1, wc = wv & 1;
  const int lrow = lane & 15, lk = lane >> 4;
  __shared__ __align__(16) hb As[128 * 128];
  __shared__ __align__(16) hb Bs[128 * 128];

  const int srow = tid >> 4;          // 0..15
  const int sc8 = tid & 15;           // 16 slots of 8 bf16
  const int sslot = (sc8 - srow) & 15;  // inverse swizzle on global source

  f32x4 acc[4][4];
#pragma unroll
  for (int mi = 0; mi < 4; ++mi)
#pragma unroll
    for (int ni = 0; ni < 4; ++ni) acc[mi][ni] = (f32x4){0.f, 0.f, 0.f, 0.f};

  long long aoff[8], boff[8];
#pragma unroll
  for (int it = 0; it < 8; ++it) {
    int gm = bm + srow + it * 16; if (gm > M - 1) gm = M - 1;
    int gn = bn + srow + it * 16; if (gn > N - 1) gn = N - 1;
    aoff[it] = (long long)gm * lda + sslot * 8;
    boff[it] = (long long)gn * ldb + sslot * 8;
  }

  for (int k0 = 0; k0 < K; k0 += 128) {
#pragma unroll
    for (int it = 0; it < 8; ++it)
      gload16(A + aoff[it] + k0, &As[(tid + it * 256) * 8]);
#pragma unroll
    for (int it = 0; it < 8; ++it)
      gload16(B + boff[it] + k0, &Bs[(tid + it * 256) * 8]);
    __syncthreads();
#pragma unroll
    for (int ks = 0; ks < 4; ++ks) {
      const int sa = ((ks * 4 + lk + lrow) & 15) * 8;   // swizzled read slot
      short8 a[4], b[4];
#pragma unroll
      for (int mi = 0; mi < 4; ++mi)
        a[mi] = *(const short8*)&As[(wr * 64 + mi * 16 + lrow) * 128 + sa];
#pragma unroll
      for (int ni = 0; ni < 4; ++ni)
        b[ni] = *(const short8*)&Bs[(wc * 64 + ni * 16 + lrow) * 128 + sa];
#pragma unroll
      for (int mi = 0; mi < 4; ++mi)
#pragma unroll
        for (int ni = 0; ni < 4; ++ni)
          acc[mi][ni] = __builtin_amdgcn_mfma_f32_16x16x32_bf16(
              a[mi], b[ni], acc[mi][ni], 0, 0, 0);
    }
    __syncthreads();
  }

  float* Cf = (float*)Cv;
  hb* Cb = (hb*)Cv;
#pragma unroll
  for (int mi = 0; mi < 4; ++mi) {
#pragma unroll
    for (int ni = 0; ni < 4; ++ni) {
#pragma unroll
      for (int q = 0; q < 4; ++q) {
        int gm = bm + wr * 64 + mi * 16 + lk * 4 + q;
        int gn = bn + wc * 64 + ni * 16 + lrow;
        if (gm < M && gn < N) {
          float v = acc[mi][ni][q];
          if (bp)   v += bp[gn];
          if (act)  v = gelu_f(v);
          long long off = cbase + (long long)gm * ldc + gn;
          if (out_mode == 1) Cb[off] = __float2bfloat16(v);
          else               Cf[off] = v;
        }
      }
    }
  }
}

// ---------------------------------------------------------------------------
// Fused split-bf16 3-term GEMM (fp32-equivalent): stages A_hi,A_lo,B_hi,B_lo
// once per K-tile (64KB LDS), 96 MFMAs per K-tile (hh + lh + hl). BK=64.
// out_mode: 0 = f32, 2 = split hi/lo bf16.
// ---------------------------------------------------------------------------
__global__ __launch_bounds__(256) void gemm_fast3(
    const hb* __restrict__ Ah, const hb* __restrict__ Al,
    const hb* __restrict__ Bh, const hb* __restrict__ Bl,
    const float* __restrict__ bias, void* __restrict__ Cv, void* __restrict__ Cv2,
    int M, int N, int K, int lda, int ldb, int ldc, int act, int out_mode)
{
  const int bm = blockIdx.y * 128, bn = blockIdx.x * 128;
  const int tid = threadIdx.x;
  const int lane = tid & 63;
  const int wv = tid >> 6, wr = wv >> 1, wc = wv & 1;
  const int lrow = lane & 15, lk = lane >> 4;
  __shared__ __align__(16) hb AsH[128 * 64];
  __shared__ __align__(16) hb AsL[128 * 64];
  __shared__ __align__(16) hb BsH[128 * 64];
  __shared__ __align__(16) hb BsL[128 * 64];

  const int srow = tid >> 3;
  const int sc8 = tid & 7;
  const int sslot = (sc8 - srow) & 7;

  f32x4 acc[4][4];
#pragma unroll
  for (int mi = 0; mi < 4; ++mi)
#pragma unroll
    for (int ni = 0; ni < 4; ++ni) acc[mi][ni] = (f32x4){0.f, 0.f, 0.f, 0.f};

  long long aoff[4], boff[4];
#pragma unroll
  for (int it = 0; it < 4; ++it) {
    int gm = bm + srow + it * 32; if (gm > M - 1) gm = M - 1;
    int gn = bn + srow + it * 32; if (gn > N - 1) gn = N - 1;
    aoff[it] = (long long)gm * lda + sslot * 8;
    boff[it] = (long long)gn * ldb + sslot * 8;
  }

  for (int k0 = 0; k0 < K; k0 += 64) {
#pragma unroll
    for (int it = 0; it < 4; ++it) {
      gload16(Ah + aoff[it] + k0, &AsH[(tid + it * 256) * 8]);
      gload16(Al + aoff[it] + k0, &AsL[(tid + it * 256) * 8]);
      gload16(Bh + boff[it] + k0, &BsH[(tid + it * 256) * 8]);
      gload16(Bl + boff[it] + k0, &BsL[(tid + it * 256) * 8]);
    }
    __syncthreads();
#pragma unroll
    for (int ks = 0; ks < 2; ++ks) {
      const int sa = ((ks * 4 + lk + lrow) & 7) * 8;
      short8 aH[4], aL[4], bH[4], bL[4];
#pragma unroll
      for (int mi = 0; mi < 4; ++mi) {
        int r = (wr * 64 + mi * 16 + lrow) * 64 + sa;
        aH[mi] = *(const short8*)&AsH[r];
        aL[mi] = *(const short8*)&AsL[r];
      }
#pragma unroll
      for (int ni = 0; ni < 4; ++ni) {
        int r = (wc * 64 + ni * 16 + lrow) * 64 + sa;
        bH[ni] = *(const short8*)&BsH[r];
        bL[ni] = *(const short8*)&BsL[r];
      }
#pragma unroll
      for (int mi = 0; mi < 4; ++mi)
#pragma unroll
        for (int ni = 0; ni < 4; ++ni) {
          acc[mi][ni] = __builtin_amdgcn_mfma_f32_16x16x32_bf16(
              aH[mi], bH[ni], acc[mi][ni], 0, 0, 0);
          acc[mi][ni] = __builtin_amdgcn_mfma_f32_16x16x32_bf16(
              aL[mi], bH[ni], acc[mi][ni], 0, 0, 0);
          acc[mi][ni] = __builtin_amdgcn_mfma_f32_16x16x32_bf16(
              aH[mi], bL[ni], acc[mi][ni], 0, 0, 0);
        }
    }
    __syncthreads();
  }

  float* Cf = (float*)Cv;
  hb* Cb = (hb*)Cv;
  hb* Cb2 = (hb*)Cv2;
#pragma unroll
  for (int mi = 0; mi < 4; ++mi) {
#pragma unroll
    for (int ni = 0; ni < 4; ++ni) {
#pragma unroll
      for (int q = 0; q < 4; ++q) {
        int gm = bm + wr * 64 + mi * 16 + lk * 4 + q;
        int gn = bn + wc * 64 + ni * 16 + lrow;
        if (gm < M && gn < N) {
          float v = acc[mi][ni][q];
          if (bias) v += bias[gn];
          if (act)  v = gelu_f(v);
          long long off = (long long)gm * ldc + gn;
          if (out_mode == 2) {
            unsigned short h = bf_bits(v);
            unsigned short l = bf_bits(v - bf_back(h));
            Cb[off] = *reinterpret_cast<hb*>(&h);
            Cb2[off] = *reinterpret_cast<hb*>(&l);
          } else {
            Cf[off] = v;
          }
        }
      }
    }
  }
}

// ---------------------------------------------------------------------------
// Banded MFMA: partial[kq][b][s][d] = proj[s].em[s+d] over K-quarter (3-term)
// (term-major k-loop kept: accumulation ORDER preserves bitwise band values;
//  selection is order-sensitive — do not restructure)
// ---------------------------------------------------------------------------
__global__ __launch_bounds__(256) void bandmm(
    const hb* __restrict__ Phi, const hb* __restrict__ Plo,
    const hb* __restrict__ Ehi, const hb* __restrict__ Elo,
    float* __restrict__ partial)
{
  const int s0 = blockIdx.x * 64;
  const int kq = blockIdx.y;
  const int b = blockIdx.z;
  const int tid = threadIdx.x;
  const int lane = tid & 63;
  const int wv = tid >> 6, wr = wv >> 1, wc = wv & 1;
  const int lrow = lane & 15, lk = lane >> 4;
  __shared__ __align__(16) hb As[64 * 64];
  __shared__ __align__(16) hb Bs[96 * 64];

  f32x4 acc[2][3];
#pragma unroll
  for (int mi = 0; mi < 2; ++mi)
#pragma unroll
    for (int ni = 0; ni < 3; ++ni) acc[mi][ni] = (f32x4){0.f, 0.f, 0.f, 0.f};

  const long long Pbase = (long long)(b * S_LEN) * FDIM;
  long long aoff[2], boff[3];
#pragma unroll
  for (int it = 0; it < 2; ++it) {
    int row = (tid + it * 256) >> 3;
    aoff[it] = Pbase + (long long)(s0 + row) * FDIM + (tid & 7) * 8;
  }
#pragma unroll
  for (int it = 0; it < 3; ++it) {
    int row = (tid + it * 256) >> 3;
    int t = s0 + row; if (t > S_LEN - 1) t = S_LEN - 1;
    boff[it] = Pbase + (long long)t * FDIM + (tid & 7) * 8;
  }

  const int kbeg = kq * (FDIM / 4), kend = kbeg + FDIM / 4;
  for (int t3 = 0; t3 < 3; ++t3) {
    const hb* Ap = (t3 == 1) ? Plo : Phi;
    const hb* Bp = (t3 == 2) ? Elo : Ehi;
    for (int k0 = kbeg; k0 < kend; k0 += 64) {
#pragma unroll
      for (int it = 0; it < 2; ++it)
        gload16(Ap + aoff[it] + k0, &As[(tid + it * 256) * 8]);
#pragma unroll
      for (int it = 0; it < 3; ++it)
        gload16(Bp + boff[it] + k0, &Bs[(tid + it * 256) * 8]);
      __syncthreads();
#pragma unroll
      for (int ks = 0; ks < 2; ++ks) {
        short8 a[2], bb[3];
#pragma unroll
        for (int mi = 0; mi < 2; ++mi)
          a[mi] = *(const short8*)&As[(wr * 32 + mi * 16 + lrow) * 64 + ks * 32 + lk * 8];
#pragma unroll
        for (int ni = 0; ni < 3; ++ni)
          bb[ni] = *(const short8*)&Bs[(wc * 48 + ni * 16 + lrow) * 64 + ks * 32 + lk * 8];
#pragma unroll
        for (int mi = 0; mi < 2; ++mi)
#pragma unroll
          for (int ni = 0; ni < 3; ++ni)
            acc[mi][ni] = __builtin_amdgcn_mfma_f32_16x16x32_bf16(
                a[mi], bb[ni], acc[mi][ni], 0, 0, 0);
      }
      __syncthreads();
    }
  }

#pragma unroll
  for (int mi = 0; mi < 2; ++mi) {
#pragma unroll
    for (int ni = 0; ni < 3; ++ni) {
#pragma unroll
      for (int q = 0; q < 4; ++q) {
        int i = wr * 32 + mi * 16 + lk * 4 + q;
        int n = wc * 48 + ni * 16 + lrow;
        int d = n - i;
        if (d >= 0 && d < 32) {
          long long off = (((long long)(kq * 2 + b)) * S_LEN + (s0 + i)) * 32 + d;
          partial[off] = acc[mi][ni][q];
        }
      }
    }
  }
}

// sum partials (fixed order), add ssc/esc, clip; -3e38 outside band.
// NOTE r6 lesson: fusing this into the 2-block select_sort serialized 8.5MB
// of traffic onto 2 CUs (+27us). Keep as its own 512-block kernel.
__global__ __launch_bounds__(256) void band_reduce(
    const float* __restrict__ partial, const float* __restrict__ ssc,
    const float* __restrict__ esc, float* __restrict__ band)
{
  int idx = blockIdx.x * 256 + threadIdx.x;
  if (idx >= BATCH * S_LEN * 32) return;
  int d = idx & 31;
  int s = (idx >> 5) & (S_LEN - 1);
  int b = idx >> 16;
  int t = s + d;
  float v;
  if (d < MAXSPAN && t < S_LEN) {
    float sum = 0.f;
#pragma unroll
    for (int kq = 0; kq < 4; ++kq)
      sum += partial[(((long long)(kq * 2 + b)) * S_LEN + s) * 32 + d];
    sum += ssc[b * S_LEN + s] + esc[b * S_LEN + t];
    v = fminf(fmaxf(sum, NEGV), -NEGV);
  } else {
    v = -3.0e38f;
  }
  band[idx] = v;
}

// ---------------------------------------------------------------------------
// Merged prep: split emb f32 -> hi/lo bf16 (first nb_split blocks) AND
// split+transpose W f32 [K][N] -> hiT/loT bf16 [N][K] (remaining blocks).
// W path uses 64k x 32n tiles with packed uint stores (128B write segments).
// nb_T host-side = (N/32)*(K/64).
// ---------------------------------------------------------------------------
__global__ __launch_bounds__(256) void prep_split(
    const float* __restrict__ emb, hb* __restrict__ hi, hb* __restrict__ lo,
    long long n4, int nb_split,
    const float* __restrict__ W, hb* __restrict__ WhiT, hb* __restrict__ WloT,
    int K, int N)
{
  if ((int)blockIdx.x < nb_split) {
    long long i = (long long)blockIdx.x * 256 + threadIdx.x;
    if (i >= n4) return;
    float4 v = ((const float4*)emb)[i];
    unsigned short h[4], l[4];
    float vv[4] = {v.x, v.y, v.z, v.w};
#pragma unroll
    for (int j = 0; j < 4; ++j) {
      h[j] = bf_bits(vv[j]);
      l[j] = bf_bits(vv[j] - bf_back(h[j]));
    }
    ((uint2*)hi)[i] = *(uint2*)h;
    ((uint2*)lo)[i] = *(uint2*)l;
    return;
  }
  __shared__ float t[64][33];
  int idx = blockIdx.x - nb_split;
  int nbx = N / 32;
  int xb = idx % nbx, yb = idx / nbx;
  int k0 = yb * 64, n0 = xb * 32;
  if (k0 >= K) return;
  int tx = threadIdx.x & 31, ty = threadIdx.x >> 5;
#pragma unroll
  for (int r = 0; r < 8; ++r)
    t[ty + r * 8][tx] = W[(long long)(k0 + ty + r * 8) * N + (n0 + tx)];
  __syncthreads();
#pragma unroll
  for (int r = 0; r < 4; ++r) {
    int n = n0 + ty + r * 8;
    float v0 = t[tx * 2][ty + r * 8];
    float v1 = t[tx * 2 + 1][ty + r * 8];
    unsigned short h0 = bf_bits(v0), h1 = bf_bits(v1);
    unsigned short l0 = bf_bits(v0 - bf_back(h0));
    unsigned short l1 = bf_bits(v1 - bf_back(h1));
    ((unsigned*)(WhiT + (long long)n * K + k0))[tx] =
        (unsigned)h0 | ((unsigned)h1 << 16);
    ((unsigned*)(WloT + (long long)n * K + k0))[tx] =
        (unsigned)l0 | ((unsigned)l1 << 16);
  }
}

// split + transpose only (s2e_W, FDIM x FDIM), 64k x 32n tiles
__global__ __launch_bounds__(256) void splitT_mat(
    const float* __restrict__ src, hb* __restrict__ hiT, hb* __restrict__ loT,
    int K, int N)
{
  __shared__ float t[64][33];
  int k0 = blockIdx.y * 64, n0 = blockIdx.x * 32;
  int tx = threadIdx.x & 31, ty = threadIdx.x >> 5;
#pragma unroll
  for (int r = 0; r < 8; ++r)
    t[ty + r * 8][tx] = src[(long long)(k0 + ty + r * 8) * N + (n0 + tx)];
  __syncthreads();
#pragma unroll
  for (int r = 0; r < 4; ++r) {
    int n = n0 + ty + r * 8;
    float v0 = t[tx * 2][ty + r * 8];
    float v1 = t[tx * 2 + 1][ty + r * 8];
    unsigned short h0 = bf_bits(v0), h1 = bf_bits(v1);
    unsigned short l0 = bf_bits(v0 - bf_back(h0));
    unsigned short l1 = bf_bits(v1 - bf_back(h1));
    ((unsigned*)(hiT + (long long)n * K + k0))[tx] =
        (unsigned)h0 | ((unsigned)h1 << 16);
    ((unsigned*)(loT + (long long)n * K + k0))[tx] =
        (unsigned)l0 | ((unsigned)l1 << 16);
  }
}

// ---------------------------------------------------------------------------
// Fused LayerNorm (fp64 stats) + hi/lo bf16 split + cls row-dot (fp64 accum)
// ---------------------------------------------------------------------------
__global__ __launch_bounds__(256) void ln_split_dot(
    const float* __restrict__ src, hb* __restrict__ hi, hb* __restrict__ lo,
    const float* __restrict__ g, const float* __restrict__ be,
    const float* __restrict__ w, const float* __restrict__ wb,
    float* __restrict__ dot_out)
{
  __shared__ float row[FDIM];
  __shared__ double scr[4];
  __shared__ double sh_mu, sh_rstd;
  const long long r = blockIdx.x;
  const float* p = src + r * FDIM;
  const int tid = threadIdx.x;

  double s = 0.0;
#pragma unroll
  for (int pp = 0; pp < 3; ++pp) {
    int c4 = pp * 256 + tid;
    float4 v = *(const float4*)(p + c4 * 4);
    *(float4*)&row[c4 * 4] = v;
    s += (double)v.x + (double)v.y + (double)v.z + (double)v.w;
  }
#pragma unroll
  for (int off = 32; off; off >>= 1) s += __shfl_down(s, off, 64);
  if ((tid & 63) == 0) scr[tid >> 6] = s;
  __syncthreads();
  if (tid == 0) sh_mu = (scr[0] + scr[1] + scr[2] + scr[3]) / FDIM;
  __syncthreads();
  double mu = sh_mu;
  double vs = 0.0;
#pragma unroll
  for (int pp = 0; pp < 12; ++pp) {
    double d = (double)row[pp * 256 + tid] - mu;
    vs += d * d;
  }
#pragma unroll
  for (int off = 32; off; off >>= 1) vs += __shfl_down(vs, off, 64);
  __syncthreads();
  if ((tid & 63) == 0) scr[tid >> 6] = vs;
  __syncthreads();
  if (tid == 0)
    sh_rstd = 1.0 / sqrt((scr[0] + scr[1] + scr[2] + scr[3]) / FDIM + 1e-5);
  __syncthreads();
  double rstd = sh_rstd;

  double dot = 0.0;
#pragma unroll
  for (int pp = 0; pp < 3; ++pp) {
    int c4 = pp * 256 + tid;
    float4 gv = *(const float4*)(g + c4 * 4);
    float4 bv = *(const float4*)(be + c4 * 4);
    float4 wv = *(const float4*)(w + c4 * 4);
    float xv[4];
    *(float4*)xv = *(const float4*)&row[c4 * 4];
    unsigned short hh[4], ll[4];
    float gg[4] = {gv.x, gv.y, gv.z, gv.w};
    float bb[4] = {bv.x, bv.y, bv.z, bv.w};
    float ww[4] = {wv.x, wv.y, wv.z, wv.w};
#pragma unroll
    for (int j = 0; j < 4; ++j) {
      float val = (float)(((double)xv[j] - mu) * rstd * (double)gg[j] + (double)bb[j]);
      dot += (double)val * (double)ww[j];
      hh[j] = bf_bits(val);
      ll[j] = bf_bits(val - bf_back(hh[j]));
    }
    *(uint2*)(hi + r * FDIM + c4 * 4) = *(uint2*)hh;
    *(uint2*)(lo + r * FDIM + c4 * 4) = *(uint2*)ll;
  }
#pragma unroll
  for (int off = 32; off; off >>= 1) dot += __shfl_down(dot, off, 64);
  __syncthreads();
  if ((tid & 63) == 0) scr[tid >> 6] = dot;
  __syncthreads();
  if (tid == 0)
    dot_out[r] = (float)(scr[0] + scr[1] + scr[2] + scr[3] + (double)wb[0]);
}

// LayerNorm f32 src -> bf16 dst, y-batched pair (phase-2)
__global__ __launch_bounds__(256) void ln_rows_bf2(
    const float* __restrict__ src0, const float* __restrict__ src1,
    hb* __restrict__ dst0, hb* __restrict__ dst1,
    const float* __restrict__ g0, const float* __restrict__ g1,
    const float* __restrict__ be0, const float* __restrict__ be1,
    int n, long long lds_, long long ldd)
{
  const int sel = blockIdx.y;
  long long r = blockIdx.x;
  const float* p = (sel ? src1 : src0) + r * lds_;
  hb* d = (sel ? dst1 : dst0) + r * ldd;
  const float* g = sel ? g1 : g0;
  const float* be = sel ? be1 : be0;
  __shared__ double scratch[4];
  __shared__ double sh_mu, sh_rstd;
  double s = 0.0;
  for (int c = threadIdx.x; c < n; c += 256) s += (double)p[c];
#pragma unroll
  for (int off = 32; off; off >>= 1) s += __shfl_down(s, off, 64);
  if ((threadIdx.x & 63) == 0) scratch[threadIdx.x >> 6] = s;
  __syncthreads();
  if (threadIdx.x == 0) sh_mu = (scratch[0] + scratch[1] + scratch[2] + scratch[3]) / n;
  __syncthreads();
  double mu = sh_mu;
  double vs = 0.0;
  for (int c = threadIdx.x; c < n; c += 256) { double dd = (double)p[c] - mu; vs += dd * dd; }
#pragma unroll
  for (int off = 32; off; off >>= 1) vs += __shfl_down(vs, off, 64);
  __syncthreads();
  if ((threadIdx.x & 63) == 0) scratch[threadIdx.x >> 6] = vs;
  __syncthreads();
  if (threadIdx.x == 0)
    sh_rstd = 1.0 / sqrt((scratch[0] + scratch[1] + scratch[2] + scratch[3]) / n + 1e-5);
  __syncthreads();
  double rstd = sh_rstd;
  for (int c = threadIdx.x; c < n; c += 256)
    d[c] = __float2bfloat16(
        (float)(((double)p[c] - mu) * rstd * (double)g[c] + (double)be[c]));
}

// ---------------------------------------------------------------------------
// Top-k selection (radix on monotone float keys) + index sort, 1 block/batch.
// Scans are LINEAR over the padded [S_LEN][32] slab (float4, coalesced).
// Pad columns hold -3e38: keys strictly below any clipped in-band value,
// and kv <= 819 << 61005 real entries, so pads can never be selected.
// ---------------------------------------------------------------------------
__device__ __forceinline__ unsigned f2k(float f) {
  unsigned u = __float_as_uint(f);
  return (u & 0x80000000u) ? ~u : (u | 0x80000000u);
}

__device__ void bitonic1024(int* a) {
  const int tid = threadIdx.x;
  for (int sz = 2; sz <= 1024; sz <<= 1) {
    for (int st = sz >> 1; st > 0; st >>= 1) {
      __syncthreads();
      int j = tid ^ st;
      if (j > tid) {
        int x = a[tid], y = a[j];
        bool asc = (tid & sz) == 0;
        if ((x > y) == asc) { a[tid] = y; a[j] = x; }
      }
    }
  }
  __syncthreads();
}

__global__ __launch_bounds__(1024) void select_sort(
    const float* __restrict__ band, const int* __restrict__ masks,
    int* __restrict__ sidx, int* __restrict__ starts, int* __restrict__ ends,
    float* __restrict__ tms, int* __restrict__ kvals)
{
  const int b = blockIdx.x;
  const int tid = threadIdx.x;
  __shared__ int hist[256];
  __shared__ int sel[1024];
  __shared__ int eq[1024];
  __shared__ int sred[16];
  __shared__ int cvar[4];
  __shared__ int cnt_gt, cnt_eq;

  int msum = 0;
  for (int i = tid; i < S_LEN; i += 1024) msum += masks[b * S_LEN + i];
#pragma unroll
  for (int off = 32; off; off >>= 1) msum += __shfl_down(msum, off, 64);
  if ((tid & 63) == 0) sred[tid >> 6] = msum;
  __syncthreads();
  if (tid == 0) {
    int t = 0;
    for (int w = 0; w < 16; ++w) t += sred[w];
    cvar[2] = t;
  }
  __syncthreads();
  int kv = (int)((float)cvar[2] * 0.4f);
  if (kv > MAXK) kv = MAXK;
  if (kv < 0) kv = 0;

  const float* bb = band + (long long)b * (S_LEN * 32);
  const float4* b4 = (const float4*)bb;
  const int N4 = S_LEN * 8;            // 16384 float4 covering padded slab
  unsigned prefix = 0u;
  int remaining = kv;

  if (kv > 0) {
    for (int byte = 3; byte >= 0; --byte) {
      if (tid < 256) hist[tid] = 0;
      __syncthreads();
      for (int i = tid; i < N4; i += 1024) {
        float4 v = b4[i];
        float vv[4] = {v.x, v.y, v.z, v.w};
#pragma unroll
        for (int j = 0; j < 4; ++j) {
          unsigned key = f2k(vv[j]);
          bool match = (byte == 3) ||
              ((key >> ((byte + 1) * 8)) == (prefix >> ((byte + 1) * 8)));
          if (match) atomicAdd(&hist[(key >> (byte * 8)) & 255], 1);
        }
      }
      __syncthreads();
      if (tid == 0) {
        int cum = 0, chosen = 255;
        for (int v = 255; v >= 0; --v) {
          int h = hist[v];
          if (cum + h >= remaining) { chosen = v; cvar[0] = remaining - cum; break; }
          cum += h;
        }
        cvar[1] = chosen;
      }
      __syncthreads();
      remaining = cvar[0];
      prefix |= ((unsigned)cvar[1]) << (byte * 8);
      __syncthreads();
    }
    if (tid == 0) { cnt_gt = 0; cnt_eq = 0; }
    __syncthreads();
    for (int i = tid; i < N4; i += 1024) {
      float4 v = b4[i];
      float vv[4] = {v.x, v.y, v.z, v.w};
#pragma unroll
      for (int j = 0; j < 4; ++j) {
        unsigned key = f2k(vv[j]);
        if (key < prefix) continue;
        int e = i * 4 + j;
        int s = e >> 5, d = e & 31;
        int flat = s * S_LEN + s + d;
        if (key > prefix) {
          int p = atomicAdd(&cnt_gt, 1);
          if (p < MAXK) sel[p] = flat;
        } else {
          int p = atomicAdd(&cnt_eq, 1);
          if (p < 1024) eq[p] = flat;
        }
      }
    }
    __syncthreads();
    int ngt = cnt_gt;
    int neq = cnt_eq; if (neq > 1024) neq = 1024;
    if (tid >= neq) eq[tid] = 0x7FFFFFFF;
    __syncthreads();
    bitonic1024(eq);
    int need = kv - ngt;
    if (tid < need) sel[ngt + tid] = eq[tid];
    __syncthreads();
  }
  if (tid >= kv && tid < MAXK) sel[tid] = S_LEN * S_LEN - 1;
  if (tid >= MAXK) sel[tid] = 0x7FFFFFFF;
  __syncthreads();
  bitonic1024(sel);
  if (tid < MAXK) {
    int idx = sel[tid];
    int s = idx >> 11;
    int t = idx & (S_LEN - 1);
    sidx[b * MAXK + tid] = idx;
    starts[b * MAXK + tid] = s;
    ends[b * MAXK + tid] = t;
    tms[b * MAXK + tid] = band[((long long)(b * S_LEN + s)) * 32 + (t - s)];
  }
  if (tid == 0) kvals[b] = kv;
}

// ---------------------------------------------------------------------------
// Merged phase-2 weight prep + gather, one node. grid (96, 48, 6):
//  z in 0..3, y<48 : transpose+convert a_{ss,es,se,ee}_W -> Wq1t/Wq2t cat
//                    (64k x 32n tiles, packed uint stores)
//  z == 4, y<16    : transpose+convert sc_W -> scWt
//  z == 4, 16<=y<32: transpose+convert ec_W -> ecWt
//  z == 4, y==32, x<24 : biasq cat = [a_ss_b+a_es_b | a_se_b+a_ee_b]
//  z == 5, u=y*96+x<3276 : gather rows (u<1638: starts->Xs, else ends->Xe)
// ---------------------------------------------------------------------------
__global__ __launch_bounds__(256) void wprep(
    const float* __restrict__ a0W, const float* __restrict__ a1W,
    const float* __restrict__ a2W, const float* __restrict__ a3W,
    hb* __restrict__ Wq1t, hb* __restrict__ Wq2t,
    const float* __restrict__ scW, const float* __restrict__ ecW,
    hb* __restrict__ scWt, hb* __restrict__ ecWt,
    const float* __restrict__ b0, const float* __restrict__ b1,
    const float* __restrict__ b2, const float* __restrict__ b3,
    float* __restrict__ biasq,
    const float* __restrict__ emb,
    const int* __restrict__ starts, const int* __restrict__ ends,
    hb* __restrict__ Xs, hb* __restrict__ Xe)
{
  __shared__ float t[64][33];
  const int z = blockIdx.z;
  int tx = threadIdx.x & 31, ty = threadIdx.x >> 5;
  if (z < 4) {
    if ((int)blockIdx.y >= FDIM / 64) return;   // defensive
    const float* src = (z == 0) ? a0W : (z == 1) ? a1W : (z == 2) ? a2W : a3W;
    hb* dst = (z < 2) ? Wq1t : Wq2t;
    const int koff = (z & 1) * FDIM;
    int k0 = blockIdx.y * 64, n0 = blockIdx.x * 32;
#pragma unroll
    for (int r = 0; r < 8; ++r)
      t[ty + r * 8][tx] = src[(long long)(k0 + ty + r * 8) * FDIM + (n0 + tx)];
    __syncthreads();
#pragma unroll
    for (int r = 0; r < 4; ++r) {
      int n = n0 + ty + r * 8;
      float v0 = t[tx * 2][ty + r * 8];
      float v1 = t[tx * 2 + 1][ty + r * 8];
      ((unsigned*)(dst + (long long)n * (2 * FDIM) + koff + k0))[tx] =
          (unsigned)bf_bits(v0) | ((unsigned)bf_bits(v1) << 16);
    }
  } else if (z == 4) {
    int yy = blockIdx.y;
    if (yy < 32) {
      const float* src = (yy < 16) ? scW : ecW;
      hb* dst = (yy < 16) ? scWt : ecWt;
      int k0 = (yy & 15) * 64, n0 = blockIdx.x * 32;
#pragma unroll
      for (int r = 0; r < 8; ++r)
        t[ty + r * 8][tx] = src[(long long)(k0 + ty + r * 8) * FDIM + (n0 + tx)];
      __syncthreads();
#pragma unroll
      for (int r = 0; r < 4; ++r) {
        int n = n0 + ty + r * 8;
        float v0 = t[tx * 2][ty + r * 8];
        float v1 = t[tx * 2 + 1][ty + r * 8];
        ((unsigned*)(dst + (long long)n * HDIM + k0))[tx] =
            (unsigned)bf_bits(v0) | ((unsigned)bf_bits(v1) << 16);
      }
    } else if (yy == 32 && blockIdx.x < 24) {
      int i = blockIdx.x * 256 + threadIdx.x;   // 0..6143
      if (i < FDIM) biasq[i] = b0[i] + b1[i];
      else          biasq[i] = b2[i - FDIM] + b3[i - FDIM];
    }
  } else {
    const int MR = BATCH * MAXK;                // 1638
    int u = blockIdx.y * (FDIM / 32) + blockIdx.x;
    if (u >= 2 * MR) return;
    int which = u >= MR;
    int g = u - which * MR;
    int b = g / MAXK;
    const int* rows = which ? ends : starts;
    hb* dst = which ? Xe : Xs;
    int r = rows[g];
    float4 v = ((const float4*)(emb + ((long long)(b * S_LEN + r)) * HDIM))[threadIdx.x];
    unsigned plo = (unsigned)bf_bits(v.x) | ((unsigned)bf_bits(v.y) << 16);
    unsigned phi = (unsigned)bf_bits(v.z) | ((unsigned)bf_bits(v.w) << 16);
    uint2 pk; pk.x = plo; pk.y = phi;
    ((uint2*)(dst + (long long)g * HDIM))[threadIdx.x] = pk;
  }
}

// out[b,i,j] assembly: sum 4 coref K-slices + pair + anaphora mask, zero last col
__global__ __launch_bounds__(256) void final_assemble(
    const float* __restrict__ coref4, const float* __restrict__ tms,
    const int* __restrict__ kvals, float* __restrict__ out)
{
  const long long SL = (long long)MAXK * MAXK;   // slice stride
  int g = blockIdx.x;                   // b*MAXK + i
  int b = g / MAXK;
  int i = g - b * MAXK;
  int kv = kvals[b];
  float ti = tms[g];
  const float* crow = coref4 + (long long)(b * 4) * SL + (long long)i * MAXK;
  float* orow = out + (long long)b * MAXK * (MAXK + 1) + (long long)i * (MAXK + 1);
  for (int j = threadIdx.x; j < MAXK + 1; j += 256) {
    float v;
    if (j == MAXK) v = 0.f;
    else {
      float c = ((crow[j] + crow[j + SL]) + (crow[j + 2 * SL] + crow[j + 3 * SL]));
      v = ti + tms[b * MAXK + j] + c;
      if (!((j < i) && (i < kv))) v += NEGV;
      v = fminf(fmaxf(v, NEGV), -NEGV);
    }
    orow[j] = v;
  }
}

// ---------------------------------------------------------------------------
static inline void launch1(const hb* A, const hb* B,
    const float* bias, const float* bias2, void* C,
    int M, int N, int K, int lda, int ldb, int ldc,
    long long sA, long long sB, long long sC,
    int act, int out_mode, int zcount, int kspl, hipStream_t stream)
{
  dim3 grid((N + 127) / 128, (M + 127) / 128, zcount);
  gemm_fast1<<<grid, 256, 0, stream>>>(A, B, bias, bias2, C, M, N, K,
                                       lda, ldb, ldc, sA, sB, sC,
                                       act, out_mode, kspl);
}

static inline void launch3(const hb* Ah, const hb* Al, const hb* Bh, const hb* Bl,
    const float* bias, void* C, void* C2, int M, int N, int K,
    int lda, int ldb, int ldc, int act, int out_mode, hipStream_t stream)
{
  dim3 grid((N + 127) / 128, (M + 127) / 128, 1);
  gemm_fast3<<<grid, 256, 0, stream>>>(Ah, Al, Bh, Bl, bias, C, C2,
                                       M, N, K, lda, ldb, ldc, act, out_mode);
}

extern "C" void kernel_launch(void* const* d_in, const int* in_sizes, int n_in,
                              void* d_out, int out_size, void* d_ws, size_t ws_size,
                              hipStream_t stream) {
  const float* input_emb = (const float*)d_in[0];
  const int*   input_masks = (const int*)d_in[1];
  const float* sm_W = (const float*)d_in[2];
  const float* sm_b = (const float*)d_in[3];
  const float* sm_g = (const float*)d_in[4];
  const float* sm_be = (const float*)d_in[5];
  const float* em_W = (const float*)d_in[6];
  const float* em_b = (const float*)d_in[7];
  const float* em_g = (const float*)d_in[8];
  const float* em_be = (const float*)d_in[9];
  const float* sc_W = (const float*)d_in[10];
  const float* sc_b = (const float*)d_in[11];
  const float* sc_g = (const float*)d_in[12];
  const float* sc_be = (const float*)d_in[13];
  const float* ec_W = (const float*)d_in[14];
  const float* ec_b = (const float*)d_in[15];
  const float* ec_g = (const float*)d_in[16];
  const float* ec_be = (const float*)d_in[17];
  const float* cls_s_W = (const float*)d_in[18];
  const float* cls_s_b = (const float*)d_in[19];
  const float* cls_e_W = (const float*)d_in[20];
  const float* cls_e_b = (const float*)d_in[21];
  const float* s2e_W = (const float*)d_in[22];
  const float* s2e_b = (const float*)d_in[23];
  const float* a_ss_W = (const float*)d_in[24];
  const float* a_ss_b = (const float*)d_in[25];
  const float* a_ee_W = (const float*)d_in[26];
  const float* a_ee_b = (const float*)d_in[27];
  const float* a_se_W = (const float*)d_in[28];
  const float* a_se_b = (const float*)d_in[29];
  const float* a_es_W = (const float*)d_in[30];
  const float* a_es_b = (const float*)d_in[31];
  float* out = (float*)d_out;

  const int NROW = BATCH * S_LEN;           // 4096
  const int MROW = BATCH * MAXK;            // 1638
  const long long SZ_BIG = (long long)NROW * FDIM * 4;      // 50331648

  char* ws = (char*)d_ws;
  // ---- phase-1 regions (schedule in launch order) ----
  float* smF    = (float*)(ws);                     // sm f32, dead after LN
  hb* sm_hi     = (hb*)(ws + 50331648LL);
  hb* sm_lo     = (hb*)(ws + 75497472LL);
  hb* emb_hi    = (hb*)(ws + 100663296LL);
  hb* emb_lo    = (hb*)(ws + 109051904LL);
  hb* w1_hiT    = (hb*)(ws + 117440512LL);
  hb* w1_loT    = (hb*)(ws + 123731968LL);
  hb* s2e_hiT   = (hb*)(ws);                        // after smF dead
  hb* s2e_loT   = (hb*)(ws + 18874368LL);
  hb* proj_hi   = (hb*)(ws + 100663296LL);          // after emb/w1 dead
  hb* proj_lo   = (hb*)(ws + 125829120LL);
  hb* emb2_hi   = (hb*)(ws);                        // after s2eT dead
  hb* emb2_lo   = (hb*)(ws + 8388608LL);
  hb* w2_hiT    = (hb*)(ws + 16777216LL);
  hb* w2_loT    = (hb*)(ws + 23068672LL);
  float* emF    = (float*)(ws + 50331648LL);        // after sm splits dead
  hb* em_hi     = (hb*)(ws);                        // after emb2/w2 dead
  hb* em_lo     = (hb*)(ws + 25165824LL);
  float* partial = (float*)(ws + 50331648LL);       // after emF dead, 2 MB
  // ---- phase-2 overlay (all weights coexist -> 1 wprep node) ----
  hb* Wq1t  = (hb*)(ws);                            // [3072][6144] cat rows 0..3071
  hb* Wq2t  = (hb*)(ws + 37748736LL);               // rows 3072..6143 (contig!)
  hb* tkcat = (hb*)(ws + 75497472LL);               // [1638][6144]
  hb* qcat  = (hb*)(ws + 95625216LL);               // live after mlp dead
  float* coref4 = (float*)(ws + 115752960LL);       // [2][4][819][819] f32
  float* mlp_s = (float*)(ws + 95625216LL);         // overlays future qcat
  float* mlp_e = (float*)(ws + 115752960LL);        // overlays future coref4
  hb* Xs_bf = (hb*)(ws + 75497472LL);               // inside future tkcat
  hb* Xe_bf = (hb*)(ws + 78852096LL);               //   (dead before tkcat write)
  hb* scWt  = (hb*)(ws + 82206720LL);
  hb* ecWt  = (hb*)(ws + 88498176LL);
  // ---- persistent tail ----
  const long long P = 3 * SZ_BIG;                   // 150994944
  float* band = (float*)(ws + P);
  float* ssc  = (float*)(ws + P + 524288);
  float* esc  = (float*)(ws + P + 540672);
  int* sidx   = (int*)(ws + P + 557056);
  int* starts = (int*)(ws + P + 565248);
  int* ends   = (int*)(ws + P + 573440);
  float* tms  = (float*)(ws + P + 581632);
  int* kvals  = (int*)(ws + P + 589824);
  float* biasq1 = (float*)(ws + P + 590080);        // [3072]
  float* biasq2 = (float*)(ws + P + 602368);        // contiguous -> [6144] cat
  (void)biasq2;
  if (ws_size < (size_t)(P + 614656)) return;

  const long long n4_emb = (long long)NROW * HDIM / 4;
  const int nb_split = (int)((n4_emb + 255) / 256);
  const int nb_T = (FDIM / 32) * (HDIM / 64);       // 64k x 32n tiles

  // ---- phase 1: selection-critical chain ----
  prep_split<<<nb_split + nb_T, 256, 0, stream>>>(
      input_emb, emb_hi, emb_lo, n4_emb, nb_split, sm_W, w1_hiT, w1_loT, HDIM, FDIM);
  launch3(emb_hi, emb_lo, w1_hiT, w1_loT, sm_b, smF, nullptr,
          NROW, FDIM, HDIM, HDIM, HDIM, FDIM, 1, 0, stream);
  ln_split_dot<<<NROW, 256, 0, stream>>>(smF, sm_hi, sm_lo, sm_g, sm_be,
                                         cls_s_W, cls_s_b, ssc);
  splitT_mat<<<dim3(FDIM / 32, FDIM / 64), 256, 0, stream>>>(s2e_W, s2e_hiT, s2e_loT, FDIM, FDIM);
  launch3(sm_hi, sm_lo, s2e_hiT, s2e_loT, s2e_b, proj_hi, proj_lo,
          NROW, FDIM, FDIM, FDIM, FDIM, FDIM, 0, 2, stream);
  prep_split<<<nb_split + nb_T, 256, 0, stream>>>(
      input_emb, emb2_hi, emb2_lo, n4_emb, nb_split, em_W, w2_hiT, w2_loT, HDIM, FDIM);
  launch3(emb2_hi, emb2_lo, w2_hiT, w2_loT, em_b, emF, nullptr,
          NROW, FDIM, HDIM, HDIM, HDIM, FDIM, 1, 0, stream);
  ln_split_dot<<<NROW, 256, 0, stream>>>(emF, em_hi, em_lo, em_g, em_be,
                                         cls_e_W, cls_e_b, esc);
  bandmm<<<dim3(S_LEN / 64, 4, BATCH), 256, 0, stream>>>(proj_hi, proj_lo, em_hi, em_lo, partial);
  band_reduce<<<(BATCH * S_LEN * 32) / 256, 256, 0, stream>>>(partial, ssc, esc, band);
  select_sort<<<BATCH, 1024, 0, stream>>>(band, input_masks, sidx, starts, ends, tms, kvals);

  // ---- phase 2 ----
  wprep<<<dim3(FDIM / 32, FDIM / 64, 6), 256, 0, stream>>>(
      a_ss_W, a_es_W, a_se_W, a_ee_W, Wq1t, Wq2t,
      sc_W, ec_W, scWt, ecWt,
      a_ss_b, a_es_b, a_se_b, a_ee_b, biasq1,
      input_emb, starts, ends, Xs_bf, Xe_bf);

  // batched mlp_s/mlp_e: z=2, contiguous operand strides, per-z bias
  launch1(Xs_bf, scWt, sc_b, ec_b, mlp_s, MROW, FDIM, HDIM, HDIM, HDIM, FDIM,
          (long long)MROW * HDIM, (long long)FDIM * HDIM, (long long)MROW * FDIM,
          1, 0, 2, 1, stream);

  ln_rows_bf2<<<dim3(MROW, 2), 256, 0, stream>>>(
      mlp_s, mlp_e, tkcat, tkcat + FDIM, sc_g, ec_g, sc_be, ec_be,
      FDIM, FDIM, 2 * FDIM);

  // fused qcat: N = 6144 over contiguous [Wq1t; Wq2t] and [biasq1|biasq2]
  launch1(tkcat, Wq1t, biasq1, nullptr, qcat, MROW, 2 * FDIM, 2 * FDIM,
          2 * FDIM, 2 * FDIM, 2 * FDIM, 0, 0, 0, 0, 1, 1, 1, stream);

  // coref: split-K x4 (K=1536/slice), batched z = b*4 + ks
  launch1(qcat, tkcat, nullptr, nullptr, coref4, MAXK, MAXK, 1536,
          2 * FDIM, 2 * FDIM, MAXK,
          (long long)MAXK * 2 * FDIM, (long long)MAXK * 2 * FDIM,
          (long long)MAXK * MAXK, 0, 0, BATCH * 4, 4, stream);

  final_assemble<<<MROW, 256, 0, stream>>>(coref4, tms, kvals, out);
}

// Round 8
// 1192.877 us; speedup vs baseline: 1.0338x; 1.0091x over previous
//
#include <hip/hip_runtime.h>
#include <hip/hip_bf16.h>
#include <math.h>

#define S_LEN 2048
#define BATCH 2
#define HDIM 1024
#define FDIM 3072
#define MAXK 819
#define MAXSPAN 30
#define NEGV -10000.0f

typedef __attribute__((ext_vector_type(8))) short short8;
typedef __attribute__((ext_vector_type(4))) float f32x4;
typedef __hip_bfloat16 hb;

__device__ __forceinline__ float gelu_f(float x) {
  return 0.5f * x * (1.0f + erff(x * 0.70710678118654752440f));
}

__device__ __forceinline__ unsigned short bf_bits(float x) {
  hb b = __float2bfloat16(x);
  return *reinterpret_cast<unsigned short*>(&b);
}
__device__ __forceinline__ float bf_back(unsigned short u) {
  hb b = *reinterpret_cast<hb*>(&u);
  return __bfloat162float(b);
}

__device__ __forceinline__ void gload16(const void* g, void* l) {
  __builtin_amdgcn_global_load_lds(
      (const __attribute__((address_space(1))) void*)g,
      (__attribute__((address_space(3))) void*)l, 16, 0, 0);
}

// ---------------------------------------------------------------------------
// bf16 MFMA GEMM, single-term, BK=128 (128 MFMA per barrier-pair).
// C[M,N] = act(A[M,K] @ B[N,K]^T + bias).  K multiple of 128.
// z-batching: blockIdx.z = zb*kspl + zk; operands at zb*sA/sB, k-slice zk,
// C slice at blockIdx.z * sC.  bias2 (if non-null) replaces bias for zb>=1.
// NOTE: XCD-chunked blockIdx remap was tried (r1/r2) and REGRESSED here:
// inputs are L3-resident and kernel is not HBM-bound; chunking de-correlates
// the XCDs' B-panel streams (FETCH 240->326 MB). Keep default dispatch order.
// NOTE r8: split-K for qcat (624-block 2-wave tail) is MEMORY-BLOCKED:
// f32 partials (80.5MB) + Wq(75.5) + tkcat(20.1) > 144MB workspace; bf16
// partials fit but add uncontrolled quantization noise into coref. Frozen.
// ---------------------------------------------------------------------------
__global__ __launch_bounds__(256) void gemm_fast1(
    const hb* __restrict__ A, const hb* __restrict__ B,
    const float* __restrict__ bias, const float* __restrict__ bias2,
    void* __restrict__ Cv,
    int M, int N, int K, int lda, int ldb, int ldc,
    long long sA, long long sB, long long sC,
    int act, int out_mode, int kspl)
{
  const int zb = blockIdx.z / kspl, zk = blockIdx.z - zb * kspl;
  A += (long long)zb * sA + (long long)zk * K;
  B += (long long)zb * sB + (long long)zk * K;
  const long long cbase = (long long)blockIdx.z * sC;
  const float* bp = (bias2 && zb) ? bias2 : bias;
  const int bm = blockIdx.y * 128, bn = blockIdx.x * 128;
  const int tid = threadIdx.x;
  const int lane = tid & 63;
  const int wv = tid >> 6, wr = wv >> 1, wc = wv & 1;
  const int lrow = lane & 15, lk = lane >> 4;
  __shared__ __align__(16) hb As[128 * 128];
  __shared__ __align__(16) hb Bs[128 * 128];

  const int srow = tid >> 4;          // 0..15
  const int sc8 = tid & 15;           // 16 slots of 8 bf16
  const int sslot = (sc8 - srow) & 15;  // inverse swizzle on global source

  f32x4 acc[4][4];
#pragma unroll
  for (int mi = 0; mi < 4; ++mi)
#pragma unroll
    for (int ni = 0; ni < 4; ++ni) acc[mi][ni] = (f32x4){0.f, 0.f, 0.f, 0.f};

  long long aoff[8], boff[8];
#pragma unroll
  for (int it = 0; it < 8; ++it) {
    int gm = bm + srow + it * 16; if (gm > M - 1) gm = M - 1;
    int gn = bn + srow + it * 16; if (gn > N - 1) gn = N - 1;
    aoff[it] = (long long)gm * lda + sslot * 8;
    boff[it] = (long long)gn * ldb + sslot * 8;
  }

  for (int k0 = 0; k0 < K; k0 += 128) {
#pragma unroll
    for (int it = 0; it < 8; ++it)
      gload16(A + aoff[it] + k0, &As[(tid + it * 256) * 8]);
#pragma unroll
    for (int it = 0; it < 8; ++it)
      gload16(B + boff[it] + k0, &Bs[(tid + it * 256) * 8]);
    __syncthreads();
#pragma unroll
    for (int ks = 0; ks < 4; ++ks) {
      const int sa = ((ks * 4 + lk + lrow) & 15) * 8;   // swizzled read slot
      short8 a[4], b[4];
#pragma unroll
      for (int mi = 0; mi < 4; ++mi)
        a[mi] = *(const short8*)&As[(wr * 64 + mi * 16 + lrow) * 128 + sa];
#pragma unroll
      for (int ni = 0; ni < 4; ++ni)
        b[ni] = *(const short8*)&Bs[(wc * 64 + ni * 16 + lrow) * 128 + sa];
#pragma unroll
      for (int mi = 0; mi < 4; ++mi)
#pragma unroll
        for (int ni = 0; ni < 4; ++ni)
          acc[mi][ni] = __builtin_amdgcn_mfma_f32_16x16x32_bf16(
              a[mi], b[ni], acc[mi][ni], 0, 0, 0);
    }
    __syncthreads();
  }

  float* Cf = (float*)Cv;
  hb* Cb = (hb*)Cv;
#pragma unroll
  for (int mi = 0; mi < 4; ++mi) {
#pragma unroll
    for (int ni = 0; ni < 4; ++ni) {
#pragma unroll
      for (int q = 0; q < 4; ++q) {
        int gm = bm + wr * 64 + mi * 16 + lk * 4 + q;
        int gn = bn + wc * 64 + ni * 16 + lrow;
        if (gm < M && gn < N) {
          float v = acc[mi][ni][q];
          if (bp)   v += bp[gn];
          if (act)  v = gelu_f(v);
          long long off = cbase + (long long)gm * ldc + gn;
          if (out_mode == 1) Cb[off] = __float2bfloat16(v);
          else               Cf[off] = v;
        }
      }
    }
  }
}

// ---------------------------------------------------------------------------
// Fused split-bf16 3-term GEMM (fp32-equivalent): stages A_hi,A_lo,B_hi,B_lo
// once per K-tile (64KB LDS), 96 MFMAs per K-tile (hh + lh + hl). BK=64.
// out_mode: 0 = f32, 2 = split hi/lo bf16.
// ---------------------------------------------------------------------------
__global__ __launch_bounds__(256) void gemm_fast3(
    const hb* __restrict__ Ah, const hb* __restrict__ Al,
    const hb* __restrict__ Bh, const hb* __restrict__ Bl,
    const float* __restrict__ bias, void* __restrict__ Cv, void* __restrict__ Cv2,
    int M, int N, int K, int lda, int ldb, int ldc, int act, int out_mode)
{
  const int bm = blockIdx.y * 128, bn = blockIdx.x * 128;
  const int tid = threadIdx.x;
  const int lane = tid & 63;
  const int wv = tid >> 6, wr = wv >> 1, wc = wv & 1;
  const int lrow = lane & 15, lk = lane >> 4;
  __shared__ __align__(16) hb AsH[128 * 64];
  __shared__ __align__(16) hb AsL[128 * 64];
  __shared__ __align__(16) hb BsH[128 * 64];
  __shared__ __align__(16) hb BsL[128 * 64];

  const int srow = tid >> 3;
  const int sc8 = tid & 7;
  const int sslot = (sc8 - srow) & 7;

  f32x4 acc[4][4];
#pragma unroll
  for (int mi = 0; mi < 4; ++mi)
#pragma unroll
    for (int ni = 0; ni < 4; ++ni) acc[mi][ni] = (f32x4){0.f, 0.f, 0.f, 0.f};

  long long aoff[4], boff[4];
#pragma unroll
  for (int it = 0; it < 4; ++it) {
    int gm = bm + srow + it * 32; if (gm > M - 1) gm = M - 1;
    int gn = bn + srow + it * 32; if (gn > N - 1) gn = N - 1;
    aoff[it] = (long long)gm * lda + sslot * 8;
    boff[it] = (long long)gn * ldb + sslot * 8;
  }

  for (int k0 = 0; k0 < K; k0 += 64) {
#pragma unroll
    for (int it = 0; it < 4; ++it) {
      gload16(Ah + aoff[it] + k0, &AsH[(tid + it * 256) * 8]);
      gload16(Al + aoff[it] + k0, &AsL[(tid + it * 256) * 8]);
      gload16(Bh + boff[it] + k0, &BsH[(tid + it * 256) * 8]);
      gload16(Bl + boff[it] + k0, &BsL[(tid + it * 256) * 8]);
    }
    __syncthreads();
#pragma unroll
    for (int ks = 0; ks < 2; ++ks) {
      const int sa = ((ks * 4 + lk + lrow) & 7) * 8;
      short8 aH[4], aL[4], bH[4], bL[4];
#pragma unroll
      for (int mi = 0; mi < 4; ++mi) {
        int r = (wr * 64 + mi * 16 + lrow) * 64 + sa;
        aH[mi] = *(const short8*)&AsH[r];
        aL[mi] = *(const short8*)&AsL[r];
      }
#pragma unroll
      for (int ni = 0; ni < 4; ++ni) {
        int r = (wc * 64 + ni * 16 + lrow) * 64 + sa;
        bH[ni] = *(const short8*)&BsH[r];
        bL[ni] = *(const short8*)&BsL[r];
      }
#pragma unroll
      for (int mi = 0; mi < 4; ++mi)
#pragma unroll
        for (int ni = 0; ni < 4; ++ni) {
          acc[mi][ni] = __builtin_amdgcn_mfma_f32_16x16x32_bf16(
              aH[mi], bH[ni], acc[mi][ni], 0, 0, 0);
          acc[mi][ni] = __builtin_amdgcn_mfma_f32_16x16x32_bf16(
              aL[mi], bH[ni], acc[mi][ni], 0, 0, 0);
          acc[mi][ni] = __builtin_amdgcn_mfma_f32_16x16x32_bf16(
              aH[mi], bL[ni], acc[mi][ni], 0, 0, 0);
        }
    }
    __syncthreads();
  }

  float* Cf = (float*)Cv;
  hb* Cb = (hb*)Cv;
  hb* Cb2 = (hb*)Cv2;
#pragma unroll
  for (int mi = 0; mi < 4; ++mi) {
#pragma unroll
    for (int ni = 0; ni < 4; ++ni) {
#pragma unroll
      for (int q = 0; q < 4; ++q) {
        int gm = bm + wr * 64 + mi * 16 + lk * 4 + q;
        int gn = bn + wc * 64 + ni * 16 + lrow;
        if (gm < M && gn < N) {
          float v = acc[mi][ni][q];
          if (bias) v += bias[gn];
          if (act)  v = gelu_f(v);
          long long off = (long long)gm * ldc + gn;
          if (out_mode == 2) {
            unsigned short h = bf_bits(v);
            unsigned short l = bf_bits(v - bf_back(h));
            Cb[off] = *reinterpret_cast<hb*>(&h);
            Cb2[off] = *reinterpret_cast<hb*>(&l);
          } else {
            Cf[off] = v;
          }
        }
      }
    }
  }
}

// ---------------------------------------------------------------------------
// Banded MFMA: partial[kq][b][s][d] = proj[s].em[s+d] over K-quarter (3-term)
// (term-major k-loop kept: accumulation ORDER preserves band values;
//  selection is order-sensitive — do not restructure)
// ---------------------------------------------------------------------------
__global__ __launch_bounds__(256) void bandmm(
    const hb* __restrict__ Phi, const hb* __restrict__ Plo,
    const hb* __restrict__ Ehi, const hb* __restrict__ Elo,
    float* __restrict__ partial)
{
  const int s0 = blockIdx.x * 64;
  const int kq = blockIdx.y;
  const int b = blockIdx.z;
  const int tid = threadIdx.x;
  const int lane = tid & 63;
  const int wv = tid >> 6, wr = wv >> 1, wc = wv & 1;
  const int lrow = lane & 15, lk = lane >> 4;
  __shared__ __align__(16) hb As[64 * 64];
  __shared__ __align__(16) hb Bs[96 * 64];

  f32x4 acc[2][3];
#pragma unroll
  for (int mi = 0; mi < 2; ++mi)
#pragma unroll
    for (int ni = 0; ni < 3; ++ni) acc[mi][ni] = (f32x4){0.f, 0.f, 0.f, 0.f};

  const long long Pbase = (long long)(b * S_LEN) * FDIM;
  long long aoff[2], boff[3];
#pragma unroll
  for (int it = 0; it < 2; ++it) {
    int row = (tid + it * 256) >> 3;
    aoff[it] = Pbase + (long long)(s0 + row) * FDIM + (tid & 7) * 8;
  }
#pragma unroll
  for (int it = 0; it < 3; ++it) {
    int row = (tid + it * 256) >> 3;
    int t = s0 + row; if (t > S_LEN - 1) t = S_LEN - 1;
    boff[it] = Pbase + (long long)t * FDIM + (tid & 7) * 8;
  }

  const int kbeg = kq * (FDIM / 4), kend = kbeg + FDIM / 4;
  for (int t3 = 0; t3 < 3; ++t3) {
    const hb* Ap = (t3 == 1) ? Plo : Phi;
    const hb* Bp = (t3 == 2) ? Elo : Ehi;
    for (int k0 = kbeg; k0 < kend; k0 += 64) {
#pragma unroll
      for (int it = 0; it < 2; ++it)
        gload16(Ap + aoff[it] + k0, &As[(tid + it * 256) * 8]);
#pragma unroll
      for (int it = 0; it < 3; ++it)
        gload16(Bp + boff[it] + k0, &Bs[(tid + it * 256) * 8]);
      __syncthreads();
#pragma unroll
      for (int ks = 0; ks < 2; ++ks) {
        short8 a[2], bb[3];
#pragma unroll
        for (int mi = 0; mi < 2; ++mi)
          a[mi] = *(const short8*)&As[(wr * 32 + mi * 16 + lrow) * 64 + ks * 32 + lk * 8];
#pragma unroll
        for (int ni = 0; ni < 3; ++ni)
          bb[ni] = *(const short8*)&Bs[(wc * 48 + ni * 16 + lrow) * 64 + ks * 32 + lk * 8];
#pragma unroll
        for (int mi = 0; mi < 2; ++mi)
#pragma unroll
          for (int ni = 0; ni < 3; ++ni)
            acc[mi][ni] = __builtin_amdgcn_mfma_f32_16x16x32_bf16(
                a[mi], bb[ni], acc[mi][ni], 0, 0, 0);
      }
      __syncthreads();
    }
  }

#pragma unroll
  for (int mi = 0; mi < 2; ++mi) {
#pragma unroll
    for (int ni = 0; ni < 3; ++ni) {
#pragma unroll
      for (int q = 0; q < 4; ++q) {
        int i = wr * 32 + mi * 16 + lk * 4 + q;
        int n = wc * 48 + ni * 16 + lrow;
        int d = n - i;
        if (d >= 0 && d < 32) {
          long long off = (((long long)(kq * 2 + b)) * S_LEN + (s0 + i)) * 32 + d;
          partial[off] = acc[mi][ni][q];
        }
      }
    }
  }
}

// sum partials (fixed order), add ssc/esc, clip; -3e38 outside band.
// NOTE r6 lesson: fusing this into the 2-block select_sort serialized 8.5MB
// of traffic onto 2 CUs (+27us). Keep as its own 512-block kernel.
__global__ __launch_bounds__(256) void band_reduce(
    const float* __restrict__ partial, const float* __restrict__ ssc,
    const float* __restrict__ esc, float* __restrict__ band)
{
  int idx = blockIdx.x * 256 + threadIdx.x;
  if (idx >= BATCH * S_LEN * 32) return;
  int d = idx & 31;
  int s = (idx >> 5) & (S_LEN - 1);
  int b = idx >> 16;
  int t = s + d;
  float v;
  if (d < MAXSPAN && t < S_LEN) {
    float sum = 0.f;
#pragma unroll
    for (int kq = 0; kq < 4; ++kq)
      sum += partial[(((long long)(kq * 2 + b)) * S_LEN + s) * 32 + d];
    sum += ssc[b * S_LEN + s] + esc[b * S_LEN + t];
    v = fminf(fmaxf(sum, NEGV), -NEGV);
  } else {
    v = -3.0e38f;
  }
  band[idx] = v;
}

// ---------------------------------------------------------------------------
// Merged prep: split emb f32 -> hi/lo bf16 (first nb_split blocks) AND
// split+transpose W f32 [K][N] -> hiT/loT bf16 [N][K] (remaining blocks).
// W path uses 64k x 32n tiles with packed uint stores (128B write segments).
// nb_T host-side = (N/32)*(K/64).
// ---------------------------------------------------------------------------
__global__ __launch_bounds__(256) void prep_split(
    const float* __restrict__ emb, hb* __restrict__ hi, hb* __restrict__ lo,
    long long n4, int nb_split,
    const float* __restrict__ W, hb* __restrict__ WhiT, hb* __restrict__ WloT,
    int K, int N)
{
  if ((int)blockIdx.x < nb_split) {
    long long i = (long long)blockIdx.x * 256 + threadIdx.x;
    if (i >= n4) return;
    float4 v = ((const float4*)emb)[i];
    unsigned short h[4], l[4];
    float vv[4] = {v.x, v.y, v.z, v.w};
#pragma unroll
    for (int j = 0; j < 4; ++j) {
      h[j] = bf_bits(vv[j]);
      l[j] = bf_bits(vv[j] - bf_back(h[j]));
    }
    ((uint2*)hi)[i] = *(uint2*)h;
    ((uint2*)lo)[i] = *(uint2*)l;
    return;
  }
  __shared__ float t[64][33];
  int idx = blockIdx.x - nb_split;
  int nbx = N / 32;
  int xb = idx % nbx, yb = idx / nbx;
  int k0 = yb * 64, n0 = xb * 32;
  if (k0 >= K) return;
  int tx = threadIdx.x & 31, ty = threadIdx.x >> 5;
#pragma unroll
  for (int r = 0; r < 8; ++r)
    t[ty + r * 8][tx] = W[(long long)(k0 + ty + r * 8) * N + (n0 + tx)];
  __syncthreads();
#pragma unroll
  for (int r = 0; r < 4; ++r) {
    int n = n0 + ty + r * 8;
    float v0 = t[tx * 2][ty + r * 8];
    float v1 = t[tx * 2 + 1][ty + r * 8];
    unsigned short h0 = bf_bits(v0), h1 = bf_bits(v1);
    unsigned short l0 = bf_bits(v0 - bf_back(h0));
    unsigned short l1 = bf_bits(v1 - bf_back(h1));
    ((unsigned*)(WhiT + (long long)n * K + k0))[tx] =
        (unsigned)h0 | ((unsigned)h1 << 16);
    ((unsigned*)(WloT + (long long)n * K + k0))[tx] =
        (unsigned)l0 | ((unsigned)l1 << 16);
  }
}

// split + transpose only (s2e_W, FDIM x FDIM), 64k x 32n tiles
__global__ __launch_bounds__(256) void splitT_mat(
    const float* __restrict__ src, hb* __restrict__ hiT, hb* __restrict__ loT,
    int K, int N)
{
  __shared__ float t[64][33];
  int k0 = blockIdx.y * 64, n0 = blockIdx.x * 32;
  int tx = threadIdx.x & 31, ty = threadIdx.x >> 5;
#pragma unroll
  for (int r = 0; r < 8; ++r)
    t[ty + r * 8][tx] = src[(long long)(k0 + ty + r * 8) * N + (n0 + tx)];
  __syncthreads();
#pragma unroll
  for (int r = 0; r < 4; ++r) {
    int n = n0 + ty + r * 8;
    float v0 = t[tx * 2][ty + r * 8];
    float v1 = t[tx * 2 + 1][ty + r * 8];
    unsigned short h0 = bf_bits(v0), h1 = bf_bits(v1);
    unsigned short l0 = bf_bits(v0 - bf_back(h0));
    unsigned short l1 = bf_bits(v1 - bf_back(h1));
    ((unsigned*)(hiT + (long long)n * K + k0))[tx] =
        (unsigned)h0 | ((unsigned)h1 << 16);
    ((unsigned*)(loT + (long long)n * K + k0))[tx] =
        (unsigned)l0 | ((unsigned)l1 << 16);
  }
}

// ---------------------------------------------------------------------------
// Fused LayerNorm (fp64 stats) + hi/lo bf16 split + cls row-dot (fp64 accum)
// PHASE-1 / selection-sensitive: summation order must not change.
// ---------------------------------------------------------------------------
__global__ __launch_bounds__(256) void ln_split_dot(
    const float* __restrict__ src, hb* __restrict__ hi, hb* __restrict__ lo,
    const float* __restrict__ g, const float* __restrict__ be,
    const float* __restrict__ w, const float* __restrict__ wb,
    float* __restrict__ dot_out)
{
  __shared__ float row[FDIM];
  __shared__ double scr[4];
  __shared__ double sh_mu, sh_rstd;
  const long long r = blockIdx.x;
  const float* p = src + r * FDIM;
  const int tid = threadIdx.x;

  double s = 0.0;
#pragma unroll
  for (int pp = 0; pp < 3; ++pp) {
    int c4 = pp * 256 + tid;
    float4 v = *(const float4*)(p + c4 * 4);
    *(float4*)&row[c4 * 4] = v;
    s += (double)v.x + (double)v.y + (double)v.z + (double)v.w;
  }
#pragma unroll
  for (int off = 32; off; off >>= 1) s += __shfl_down(s, off, 64);
  if ((tid & 63) == 0) scr[tid >> 6] = s;
  __syncthreads();
  if (tid == 0) sh_mu = (scr[0] + scr[1] + scr[2] + scr[3]) / FDIM;
  __syncthreads();
  double mu = sh_mu;
  double vs = 0.0;
#pragma unroll
  for (int pp = 0; pp < 12; ++pp) {
    double d = (double)row[pp * 256 + tid] - mu;
    vs += d * d;
  }
#pragma unroll
  for (int off = 32; off; off >>= 1) vs += __shfl_down(vs, off, 64);
  __syncthreads();
  if ((tid & 63) == 0) scr[tid >> 6] = vs;
  __syncthreads();
  if (tid == 0)
    sh_rstd = 1.0 / sqrt((scr[0] + scr[1] + scr[2] + scr[3]) / FDIM + 1e-5);
  __syncthreads();
  double rstd = sh_rstd;

  double dot = 0.0;
#pragma unroll
  for (int pp = 0; pp < 3; ++pp) {
    int c4 = pp * 256 + tid;
    float4 gv = *(const float4*)(g + c4 * 4);
    float4 bv = *(const float4*)(be + c4 * 4);
    float4 wv = *(const float4*)(w + c4 * 4);
    float xv[4];
    *(float4*)xv = *(const float4*)&row[c4 * 4];
    unsigned short hh[4], ll[4];
    float gg[4] = {gv.x, gv.y, gv.z, gv.w};
    float bb[4] = {bv.x, bv.y, bv.z, bv.w};
    float ww[4] = {wv.x, wv.y, wv.z, wv.w};
#pragma unroll
    for (int j = 0; j < 4; ++j) {
      float val = (float)(((double)xv[j] - mu) * rstd * (double)gg[j] + (double)bb[j]);
      dot += (double)val * (double)ww[j];
      hh[j] = bf_bits(val);
      ll[j] = bf_bits(val - bf_back(hh[j]));
    }
    *(uint2*)(hi + r * FDIM + c4 * 4) = *(uint2*)hh;
    *(uint2*)(lo + r * FDIM + c4 * 4) = *(uint2*)ll;
  }
#pragma unroll
  for (int off = 32; off; off >>= 1) dot += __shfl_down(dot, off, 64);
  __syncthreads();
  if ((tid & 63) == 0) scr[tid >> 6] = dot;
  __syncthreads();
  if (tid == 0)
    dot_out[r] = (float)(scr[0] + scr[1] + scr[2] + scr[3] + (double)wb[0]);
}

// LayerNorm f32 src -> bf16 dst, y-batched pair. PHASE-2 (post-selection):
// summation-order change from vectorization is tolerance-safe (r8).
__global__ __launch_bounds__(256) void ln_rows_bf2(
    const float* __restrict__ src0, const float* __restrict__ src1,
    hb* __restrict__ dst0, hb* __restrict__ dst1,
    const float* __restrict__ g0, const float* __restrict__ g1,
    const float* __restrict__ be0, const float* __restrict__ be1,
    int n, long long lds_, long long ldd)
{
  const int sel = blockIdx.y;
  long long r = blockIdx.x;
  const float* p = (sel ? src1 : src0) + r * lds_;
  hb* d = (sel ? dst1 : dst0) + r * ldd;
  const float* g = sel ? g1 : g0;
  const float* be = sel ? be1 : be0;
  __shared__ double scratch[4];
  __shared__ double sh_mu, sh_rstd;
  const int n4 = n >> 2;
  const float4* p4 = (const float4*)p;
  double s = 0.0;
  for (int c = threadIdx.x; c < n4; c += 256) {
    float4 v = p4[c];
    s += (double)v.x + (double)v.y + (double)v.z + (double)v.w;
  }
#pragma unroll
  for (int off = 32; off; off >>= 1) s += __shfl_down(s, off, 64);
  if ((threadIdx.x & 63) == 0) scratch[threadIdx.x >> 6] = s;
  __syncthreads();
  if (threadIdx.x == 0) sh_mu = (scratch[0] + scratch[1] + scratch[2] + scratch[3]) / n;
  __syncthreads();
  double mu = sh_mu;
  double vs = 0.0;
  for (int c = threadIdx.x; c < n4; c += 256) {
    float4 v = p4[c];
    double d0 = (double)v.x - mu, d1 = (double)v.y - mu;
    double d2 = (double)v.z - mu, d3 = (double)v.w - mu;
    vs += d0 * d0 + d1 * d1 + d2 * d2 + d3 * d3;
  }
#pragma unroll
  for (int off = 32; off; off >>= 1) vs += __shfl_down(vs, off, 64);
  __syncthreads();
  if ((threadIdx.x & 63) == 0) scratch[threadIdx.x >> 6] = vs;
  __syncthreads();
  if (threadIdx.x == 0)
    sh_rstd = 1.0 / sqrt((scratch[0] + scratch[1] + scratch[2] + scratch[3]) / n + 1e-5);
  __syncthreads();
  double rstd = sh_rstd;
  for (int c = threadIdx.x; c < n4; c += 256) {
    float4 v = p4[c];
    float4 gv = ((const float4*)g)[c];
    float4 bv = ((const float4*)be)[c];
    unsigned short o0 = bf_bits((float)(((double)v.x - mu) * rstd * (double)gv.x + (double)bv.x));
    unsigned short o1 = bf_bits((float)(((double)v.y - mu) * rstd * (double)gv.y + (double)bv.y));
    unsigned short o2 = bf_bits((float)(((double)v.z - mu) * rstd * (double)gv.z + (double)bv.z));
    unsigned short o3 = bf_bits((float)(((double)v.w - mu) * rstd * (double)gv.w + (double)bv.w));
    uint2 pk;
    pk.x = (unsigned)o0 | ((unsigned)o1 << 16);
    pk.y = (unsigned)o2 | ((unsigned)o3 << 16);
    *(uint2*)(d + c * 4) = pk;
  }
}

// ---------------------------------------------------------------------------
// Top-k selection (radix on monotone float keys) + index sort, 1 block/batch.
// Scans are LINEAR over the padded [S_LEN][32] slab (float4, coalesced).
// Pad columns hold -3e38: keys strictly below any clipped in-band value,
// and kv <= 819 << 61005 real entries, so pads can never be selected.
// r8: eq-tie bitonic sort SKIPPED when the whole tie bucket is consumed
// (need == neq) — order irrelevant since sel is fully sorted afterwards.
// ---------------------------------------------------------------------------
__device__ __forceinline__ unsigned f2k(float f) {
  unsigned u = __float_as_uint(f);
  return (u & 0x80000000u) ? ~u : (u | 0x80000000u);
}

__device__ void bitonic1024(int* a) {
  const int tid = threadIdx.x;
  for (int sz = 2; sz <= 1024; sz <<= 1) {
    for (int st = sz >> 1; st > 0; st >>= 1) {
      __syncthreads();
      int j = tid ^ st;
      if (j > tid) {
        int x = a[tid], y = a[j];
        bool asc = (tid & sz) == 0;
        if ((x > y) == asc) { a[tid] = y; a[j] = x; }
      }
    }
  }
  __syncthreads();
}

__global__ __launch_bounds__(1024) void select_sort(
    const float* __restrict__ band, const int* __restrict__ masks,
    int* __restrict__ sidx, int* __restrict__ starts, int* __restrict__ ends,
    float* __restrict__ tms, int* __restrict__ kvals)
{
  const int b = blockIdx.x;
  const int tid = threadIdx.x;
  __shared__ int hist[256];
  __shared__ int sel[1024];
  __shared__ int eq[1024];
  __shared__ int sred[16];
  __shared__ int cvar[4];
  __shared__ int cnt_gt, cnt_eq;

  int msum = 0;
  for (int i = tid; i < S_LEN; i += 1024) msum += masks[b * S_LEN + i];
#pragma unroll
  for (int off = 32; off; off >>= 1) msum += __shfl_down(msum, off, 64);
  if ((tid & 63) == 0) sred[tid >> 6] = msum;
  __syncthreads();
  if (tid == 0) {
    int t = 0;
    for (int w = 0; w < 16; ++w) t += sred[w];
    cvar[2] = t;
  }
  __syncthreads();
  int kv = (int)((float)cvar[2] * 0.4f);
  if (kv > MAXK) kv = MAXK;
  if (kv < 0) kv = 0;

  const float* bb = band + (long long)b * (S_LEN * 32);
  const float4* b4 = (const float4*)bb;
  const int N4 = S_LEN * 8;            // 16384 float4 covering padded slab
  unsigned prefix = 0u;
  int remaining = kv;

  if (kv > 0) {
    for (int byte = 3; byte >= 0; --byte) {
      if (tid < 256) hist[tid] = 0;
      __syncthreads();
      for (int i = tid; i < N4; i += 1024) {
        float4 v = b4[i];
        float vv[4] = {v.x, v.y, v.z, v.w};
#pragma unroll
        for (int j = 0; j < 4; ++j) {
          unsigned key = f2k(vv[j]);
          bool match = (byte == 3) ||
              ((key >> ((byte + 1) * 8)) == (prefix >> ((byte + 1) * 8)));
          if (match) atomicAdd(&hist[(key >> (byte * 8)) & 255], 1);
        }
      }
      __syncthreads();
      if (tid == 0) {
        int cum = 0, chosen = 255;
        for (int v = 255; v >= 0; --v) {
          int h = hist[v];
          if (cum + h >= remaining) { chosen = v; cvar[0] = remaining - cum; break; }
          cum += h;
        }
        cvar[1] = chosen;
      }
      __syncthreads();
      remaining = cvar[0];
      prefix |= ((unsigned)cvar[1]) << (byte * 8);
      __syncthreads();
    }
    if (tid == 0) { cnt_gt = 0; cnt_eq = 0; }
    __syncthreads();
    for (int i = tid; i < N4; i += 1024) {
      float4 v = b4[i];
      float vv[4] = {v.x, v.y, v.z, v.w};
#pragma unroll
      for (int j = 0; j < 4; ++j) {
        unsigned key = f2k(vv[j]);
        if (key < prefix) continue;
        int e = i * 4 + j;
        int s = e >> 5, d = e & 31;
        int flat = s * S_LEN + s + d;
        if (key > prefix) {
          int p = atomicAdd(&cnt_gt, 1);
          if (p < MAXK) sel[p] = flat;
        } else {
          int p = atomicAdd(&cnt_eq, 1);
          if (p < 1024) eq[p] = flat;
        }
      }
    }
    __syncthreads();
    int ngt = cnt_gt;
    int neq = cnt_eq; if (neq > 1024) neq = 1024;
    int need = kv - ngt;
    if (need > neq) need = neq;           // defensive (invariant: need <= neq)
    if (need < neq) {                     // block-uniform condition
      if (tid >= neq) eq[tid] = 0x7FFFFFFF;
      __syncthreads();
      bitonic1024(eq);                    // pick smallest `need` tie indices
    }
    if (tid < need) sel[ngt + tid] = eq[tid];
    __syncthreads();
  }
  if (tid >= kv && tid < MAXK) sel[tid] = S_LEN * S_LEN - 1;
  if (tid >= MAXK) sel[tid] = 0x7FFFFFFF;
  __syncthreads();
  bitonic1024(sel);
  if (tid < MAXK) {
    int idx = sel[tid];
    int s = idx >> 11;
    int t = idx & (S_LEN - 1);
    sidx[b * MAXK + tid] = idx;
    starts[b * MAXK + tid] = s;
    ends[b * MAXK + tid] = t;
    tms[b * MAXK + tid] = band[((long long)(b * S_LEN + s)) * 32 + (t - s)];
  }
  if (tid == 0) kvals[b] = kv;
}

// ---------------------------------------------------------------------------
// Merged phase-2 weight prep + gather, one node. grid (96, 48, 6):
//  z in 0..3, y<48 : transpose+convert a_{ss,es,se,ee}_W -> Wq1t/Wq2t cat
//                    (64k x 32n tiles, packed uint stores)
//  z == 4, y<16    : transpose+convert sc_W -> scWt
//  z == 4, 16<=y<32: transpose+convert ec_W -> ecWt
//  z == 4, y==32, x<24 : biasq cat = [a_ss_b+a_es_b | a_se_b+a_ee_b]
//  z == 5, u=y*96+x<3276 : gather rows (u<1638: starts->Xs, else ends->Xe)
// ---------------------------------------------------------------------------
__global__ __launch_bounds__(256) void wprep(
    const float* __restrict__ a0W, const float* __restrict__ a1W,
    const float* __restrict__ a2W, const float* __restrict__ a3W,
    hb* __restrict__ Wq1t, hb* __restrict__ Wq2t,
    const float* __restrict__ scW, const float* __restrict__ ecW,
    hb* __restrict__ scWt, hb* __restrict__ ecWt,
    const float* __restrict__ b0, const float* __restrict__ b1,
    const float* __restrict__ b2, const float* __restrict__ b3,
    float* __restrict__ biasq,
    const float* __restrict__ emb,
    const int* __restrict__ starts, const int* __restrict__ ends,
    hb* __restrict__ Xs, hb* __restrict__ Xe)
{
  __shared__ float t[64][33];
  const int z = blockIdx.z;
  int tx = threadIdx.x & 31, ty = threadIdx.x >> 5;
  if (z < 4) {
    if ((int)blockIdx.y >= FDIM / 64) return;   // defensive
    const float* src = (z == 0) ? a0W : (z == 1) ? a1W : (z == 2) ? a2W : a3W;
    hb* dst = (z < 2) ? Wq1t : Wq2t;
    const int koff = (z & 1) * FDIM;
    int k0 = blockIdx.y * 64, n0 = blockIdx.x * 32;
#pragma unroll
    for (int r = 0; r < 8; ++r)
      t[ty + r * 8][tx] = src[(long long)(k0 + ty + r * 8) * FDIM + (n0 + tx)];
    __syncthreads();
#pragma unroll
    for (int r = 0; r < 4; ++r) {
      int n = n0 + ty + r * 8;
      float v0 = t[tx * 2][ty + r * 8];
      float v1 = t[tx * 2 + 1][ty + r * 8];
      ((unsigned*)(dst + (long long)n * (2 * FDIM) + koff + k0))[tx] =
          (unsigned)bf_bits(v0) | ((unsigned)bf_bits(v1) << 16);
    }
  } else if (z == 4) {
    int yy = blockIdx.y;
    if (yy < 32) {
      const float* src = (yy < 16) ? scW : ecW;
      hb* dst = (yy < 16) ? scWt : ecWt;
      int k0 = (yy & 15) * 64, n0 = blockIdx.x * 32;
#pragma unroll
      for (int r = 0; r < 8; ++r)
        t[ty + r * 8][tx] = src[(long long)(k0 + ty + r * 8) * FDIM + (n0 + tx)];
      __syncthreads();
#pragma unroll
      for (int r = 0; r < 4; ++r) {
        int n = n0 + ty + r * 8;
        float v0 = t[tx * 2][ty + r * 8];
        float v1 = t[tx * 2 + 1][ty + r * 8];
        ((unsigned*)(dst + (long long)n * HDIM + k0))[tx] =
            (unsigned)bf_bits(v0) | ((unsigned)bf_bits(v1) << 16);
      }
    } else if (yy == 32 && blockIdx.x < 24) {
      int i = blockIdx.x * 256 + threadIdx.x;   // 0..6143
      if (i < FDIM) biasq[i] = b0[i] + b1[i];
      else          biasq[i] = b2[i - FDIM] + b3[i - FDIM];
    }
  } else {
    const int MR = BATCH * MAXK;                // 1638
    int u = blockIdx.y * (FDIM / 32) + blockIdx.x;
    if (u >= 2 * MR) return;
    int which = u >= MR;
    int g = u - which * MR;
    int b = g / MAXK;
    const int* rows = which ? ends : starts;
    hb* dst = which ? Xe : Xs;
    int r = rows[g];
    float4 v = ((const float4*)(emb + ((long long)(b * S_LEN + r)) * HDIM))[threadIdx.x];
    unsigned plo = (unsigned)bf_bits(v.x) | ((unsigned)bf_bits(v.y) << 16);
    unsigned phi = (unsigned)bf_bits(v.z) | ((unsigned)bf_bits(v.w) << 16);
    uint2 pk; pk.x = plo; pk.y = phi;
    ((uint2*)(dst + (long long)g * HDIM))[threadIdx.x] = pk;
  }
}

// out[b,i,j] assembly: sum 4 coref K-slices + pair + anaphora mask, zero last col
__global__ __launch_bounds__(256) void final_assemble(
    const float* __restrict__ coref4, const float* __restrict__ tms,
    const int* __restrict__ kvals, float* __restrict__ out)
{
  const long long SL = (long long)MAXK * MAXK;   // slice stride
  int g = blockIdx.x;                   // b*MAXK + i
  int b = g / MAXK;
  int i = g - b * MAXK;
  int kv = kvals[b];
  float ti = tms[g];
  const float* crow = coref4 + (long long)(b * 4) * SL + (long long)i * MAXK;
  float* orow = out + (long long)b * MAXK * (MAXK + 1) + (long long)i * (MAXK + 1);
  for (int j = threadIdx.x; j < MAXK + 1; j += 256) {
    float v;
    if (j == MAXK) v = 0.f;
    else {
      float c = ((crow[j] + crow[j + SL]) + (crow[j + 2 * SL] + crow[j + 3 * SL]));
      v = ti + tms[b * MAXK + j] + c;
      if (!((j < i) && (i < kv))) v += NEGV;
      v = fminf(fmaxf(v, NEGV), -NEGV);
    }
    orow[j] = v;
  }
}

// ---------------------------------------------------------------------------
static inline void launch1(const hb* A, const hb* B,
    const float* bias, const float* bias2, void* C,
    int M, int N, int K, int lda, int ldb, int ldc,
    long long sA, long long sB, long long sC,
    int act, int out_mode, int zcount, int kspl, hipStream_t stream)
{
  dim3 grid((N + 127) / 128, (M + 127) / 128, zcount);
  gemm_fast1<<<grid, 256, 0, stream>>>(A, B, bias, bias2, C, M, N, K,
                                       lda, ldb, ldc, sA, sB, sC,
                                       act, out_mode, kspl);
}

static inline void launch3(const hb* Ah, const hb* Al, const hb* Bh, const hb* Bl,
    const float* bias, void* C, void* C2, int M, int N, int K,
    int lda, int ldb, int ldc, int act, int out_mode, hipStream_t stream)
{
  dim3 grid((N + 127) / 128, (M + 127) / 128, 1);
  gemm_fast3<<<grid, 256, 0, stream>>>(Ah, Al, Bh, Bl, bias, C, C2,
                                       M, N, K, lda, ldb, ldc, act, out_mode);
}

extern "C" void kernel_launch(void* const* d_in, const int* in_sizes, int n_in,
                              void* d_out, int out_size, void* d_ws, size_t ws_size,
                              hipStream_t stream) {
  const float* input_emb = (const float*)d_in[0];
  const int*   input_masks = (const int*)d_in[1];
  const float* sm_W = (const float*)d_in[2];
  const float* sm_b = (const float*)d_in[3];
  const float* sm_g = (const float*)d_in[4];
  const float* sm_be = (const float*)d_in[5];
  const float* em_W = (const float*)d_in[6];
  const float* em_b = (const float*)d_in[7];
  const float* em_g = (const float*)d_in[8];
  const float* em_be = (const float*)d_in[9];
  const float* sc_W = (const float*)d_in[10];
  const float* sc_b = (const float*)d_in[11];
  const float* sc_g = (const float*)d_in[12];
  const float* sc_be = (const float*)d_in[13];
  const float* ec_W = (const float*)d_in[14];
  const float* ec_b = (const float*)d_in[15];
  const float* ec_g = (const float*)d_in[16];
  const float* ec_be = (const float*)d_in[17];
  const float* cls_s_W = (const float*)d_in[18];
  const float* cls_s_b = (const float*)d_in[19];
  const float* cls_e_W = (const float*)d_in[20];
  const float* cls_e_b = (const float*)d_in[21];
  const float* s2e_W = (const float*)d_in[22];
  const float* s2e_b = (const float*)d_in[23];
  const float* a_ss_W = (const float*)d_in[24];
  const float* a_ss_b = (const float*)d_in[25];
  const float* a_ee_W = (const float*)d_in[26];
  const float* a_ee_b = (const float*)d_in[27];
  const float* a_se_W = (const float*)d_in[28];
  const float* a_se_b = (const float*)d_in[29];
  const float* a_es_W = (const float*)d_in[30];
  const float* a_es_b = (const float*)d_in[31];
  float* out = (float*)d_out;

  const int NROW = BATCH * S_LEN;           // 4096
  const int MROW = BATCH * MAXK;            // 1638
  const long long SZ_BIG = (long long)NROW * FDIM * 4;      // 50331648

  char* ws = (char*)d_ws;
  // ---- phase-1 regions (schedule in launch order) ----
  float* smF    = (float*)(ws);                     // sm f32, dead after LN
  hb* sm_hi     = (hb*)(ws + 50331648LL);
  hb* sm_lo     = (hb*)(ws + 75497472LL);
  hb* emb_hi    = (hb*)(ws + 100663296LL);
  hb* emb_lo    = (hb*)(ws + 109051904LL);
  hb* w1_hiT    = (hb*)(ws + 117440512LL);
  hb* w1_loT    = (hb*)(ws + 123731968LL);
  hb* s2e_hiT   = (hb*)(ws);                        // after smF dead
  hb* s2e_loT   = (hb*)(ws + 18874368LL);
  hb* proj_hi   = (hb*)(ws + 100663296LL);          // after emb/w1 dead
  hb* proj_lo   = (hb*)(ws + 125829120LL);
  hb* emb2_hi   = (hb*)(ws);                        // after s2eT dead
  hb* emb2_lo   = (hb*)(ws + 8388608LL);
  hb* w2_hiT    = (hb*)(ws + 16777216LL);
  hb* w2_loT    = (hb*)(ws + 23068672LL);
  float* emF    = (float*)(ws + 50331648LL);        // after sm splits dead
  hb* em_hi     = (hb*)(ws);                        // after emb2/w2 dead
  hb* em_lo     = (hb*)(ws + 25165824LL);
  float* partial = (float*)(ws + 50331648LL);       // after emF dead, 2 MB
  // ---- phase-2 overlay (all weights coexist -> 1 wprep node) ----
  hb* Wq1t  = (hb*)(ws);                            // [3072][6144] cat rows 0..3071
  hb* Wq2t  = (hb*)(ws + 37748736LL);               // rows 3072..6143 (contig!)
  hb* tkcat = (hb*)(ws + 75497472LL);               // [1638][6144]
  hb* qcat  = (hb*)(ws + 95625216LL);               // live after mlp dead
  float* coref4 = (float*)(ws + 115752960LL);       // [2][4][819][819] f32
  float* mlp_s = (float*)(ws + 95625216LL);         // overlays future qcat
  float* mlp_e = (float*)(ws + 115752960LL);        // overlays future coref4
  hb* Xs_bf = (hb*)(ws + 75497472LL);               // inside future tkcat
  hb* Xe_bf = (hb*)(ws + 78852096LL);               //   (dead before tkcat write)
  hb* scWt  = (hb*)(ws + 82206720LL);
  hb* ecWt  = (hb*)(ws + 88498176LL);
  // ---- persistent tail ----
  const long long P = 3 * SZ_BIG;                   // 150994944
  float* band = (float*)(ws + P);
  float* ssc  = (float*)(ws + P + 524288);
  float* esc  = (float*)(ws + P + 540672);
  int* sidx   = (int*)(ws + P + 557056);
  int* starts = (int*)(ws + P + 565248);
  int* ends   = (int*)(ws + P + 573440);
  float* tms  = (float*)(ws + P + 581632);
  int* kvals  = (int*)(ws + P + 589824);
  float* biasq1 = (float*)(ws + P + 590080);        // [3072]
  float* biasq2 = (float*)(ws + P + 602368);        // contiguous -> [6144] cat
  (void)biasq2;
  if (ws_size < (size_t)(P + 614656)) return;

  const long long n4_emb = (long long)NROW * HDIM / 4;
  const int nb_split = (int)((n4_emb + 255) / 256);
  const int nb_T = (FDIM / 32) * (HDIM / 64);       // 64k x 32n tiles

  // ---- phase 1: selection-critical chain ----
  prep_split<<<nb_split + nb_T, 256, 0, stream>>>(
      input_emb, emb_hi, emb_lo, n4_emb, nb_split, sm_W, w1_hiT, w1_loT, HDIM, FDIM);
  launch3(emb_hi, emb_lo, w1_hiT, w1_loT, sm_b, smF, nullptr,
          NROW, FDIM, HDIM, HDIM, HDIM, FDIM, 1, 0, stream);
  ln_split_dot<<<NROW, 256, 0, stream>>>(smF, sm_hi, sm_lo, sm_g, sm_be,
                                         cls_s_W, cls_s_b, ssc);
  splitT_mat<<<dim3(FDIM / 32, FDIM / 64), 256, 0, stream>>>(s2e_W, s2e_hiT, s2e_loT, FDIM, FDIM);
  launch3(sm_hi, sm_lo, s2e_hiT, s2e_loT, s2e_b, proj_hi, proj_lo,
          NROW, FDIM, FDIM, FDIM, FDIM, FDIM, 0, 2, stream);
  prep_split<<<nb_split + nb_T, 256, 0, stream>>>(
      input_emb, emb2_hi, emb2_lo, n4_emb, nb_split, em_W, w2_hiT, w2_loT, HDIM, FDIM);
  launch3(emb2_hi, emb2_lo, w2_hiT, w2_loT, em_b, emF, nullptr,
          NROW, FDIM, HDIM, HDIM, HDIM, FDIM, 1, 0, stream);
  ln_split_dot<<<NROW, 256, 0, stream>>>(emF, em_hi, em_lo, em_g, em_be,
                                         cls_e_W, cls_e_b, esc);
  bandmm<<<dim3(S_LEN / 64, 4, BATCH), 256, 0, stream>>>(proj_hi, proj_lo, em_hi, em_lo, partial);
  band_reduce<<<(BATCH * S_LEN * 32) / 256, 256, 0, stream>>>(partial, ssc, esc, band);
  select_sort<<<BATCH, 1024, 0, stream>>>(band, input_masks, sidx, starts, ends, tms, kvals);

  // ---- phase 2 ----
  wprep<<<dim3(FDIM / 32, FDIM / 64, 6), 256, 0, stream>>>(
      a_ss_W, a_es_W, a_se_W, a_ee_W, Wq1t, Wq2t,
      sc_W, ec_W, scWt, ecWt,
      a_ss_b, a_es_b, a_se_b, a_ee_b, biasq1,
      input_emb, starts, ends, Xs_bf, Xe_bf);

  // batched mlp_s/mlp_e: z=2, contiguous operand strides, per-z bias
  launch1(Xs_bf, scWt, sc_b, ec_b, mlp_s, MROW, FDIM, HDIM, HDIM, HDIM, FDIM,
          (long long)MROW * HDIM, (long long)FDIM * HDIM, (long long)MROW * FDIM,
          1, 0, 2, 1, stream);

  ln_rows_bf2<<<dim3(MROW, 2), 256, 0, stream>>>(
      mlp_s, mlp_e, tkcat, tkcat + FDIM, sc_g, ec_g, sc_be, ec_be,
      FDIM, FDIM, 2 * FDIM);

  // fused qcat: N = 6144 over contiguous [Wq1t; Wq2t] and [biasq1|biasq2]
  launch1(tkcat, Wq1t, biasq1, nullptr, qcat, MROW, 2 * FDIM, 2 * FDIM,
          2 * FDIM, 2 * FDIM, 2 * FDIM, 0, 0, 0, 0, 1, 1, 1, stream);

  // coref: split-K x4 (K=1536/slice), batched z = b*4 + ks
  launch1(qcat, tkcat, nullptr, nullptr, coref4, MAXK, MAXK, 1536,
          2 * FDIM, 2 * FDIM, MAXK,
          (long long)MAXK * 2 * FDIM, (long long)MAXK * 2 * FDIM,
          (long long)MAXK * MAXK, 0, 0, BATCH * 4, 4, stream);

  final_assemble<<<MROW, 256, 0, stream>>>(coref4, tms, kvals, out);
}